// Round 16
// baseline (3137.989 us; speedup 1.0000x reference)
//
#include <hip/hip_runtime.h>
#include <hip/hip_bf16.h>
#include <stdint.h>

#define S_ 64
#define B_ 64
#define E_ 512
#define H_ 512
#define V_ 32000
#define G4 2048   // 4*H
#define SB 4096   // S*B

// d_out row = 32000 fp32 = 64000 ushort; G0 (bf16) lives in the tail 4096
// ushorts of each row: G0(sb, d, c) at ushort index sb*64000 + 59904 + d*2048 + c.
// Sequential structure: final GEMM runs after rec and overwrites the tails.
#define OROW_US 64000
#define GTAIL_US 59904   // 29952 fp32 * 2

typedef __attribute__((ext_vector_type(8))) short short8;
typedef __attribute__((ext_vector_type(4))) float f32x4;
typedef __attribute__((ext_vector_type(4))) int i32x4;

static __device__ __forceinline__ unsigned short f2bf(float f) {
  unsigned u = __float_as_uint(f);
  u += 0x7fff + ((u >> 16) & 1);   // RNE
  return (unsigned short)(u >> 16);
}
static __device__ __forceinline__ unsigned pk2(float a, float b) {
  return (unsigned)f2bf(a) | ((unsigned)f2bf(b) << 16);
}
static __device__ __forceinline__ float bf2f(unsigned short u) {
  return __uint_as_float((unsigned)u << 16);
}
static __device__ __forceinline__ float sigm(float x) {
  return 1.f / (1.f + expf(-x));
}

__device__ __forceinline__ void gload_lds16(const void* g, void* l) {
  __builtin_amdgcn_global_load_lds(
      (const __attribute__((address_space(1))) void*)g,
      (__attribute__((address_space(3))) void*)l, 16, 0, 0);
}

// coherent (device-visible) 16-byte store: write-through past the XCD L2
__device__ __forceinline__ void st128_sys(void* p, i32x4 v) {
  asm volatile("global_store_dwordx4 %0, %1, off sc0 sc1"
               :: "v"((unsigned long long)p), "v"(v) : "memory");
}
__device__ __forceinline__ void wait_vm0() {
  asm volatile("s_waitcnt vmcnt(0)" ::: "memory");
}

__device__ __forceinline__ void spin_ge(unsigned* c, unsigned tgt) {
  while (__hip_atomic_load(c, __ATOMIC_RELAXED, __HIP_MEMORY_SCOPE_AGENT) < tgt)
    __builtin_amdgcn_s_sleep(1);
}
__device__ __forceinline__ void arrive(unsigned* c) {
  __hip_atomic_fetch_add(c, 1u, __ATOMIC_RELAXED, __HIP_MEMORY_SCOPE_AGENT);
}

// counter slot: per (step, dir), 256B apart
#define CIDX(t, d, p) ((((t) * 8) + ((d) * 4) + (p)) * 64)
#define CNT_BYTES (64 * 8 * 64 * 4)

// ---- merged fp32->bf16 for the four LSTM weight tensors (contiguous dst) ----
__global__ void k_f2bf4(const float* __restrict__ s0, const float* __restrict__ s1,
                        const float* __restrict__ s2, const float* __restrict__ s3,
                        unsigned short* __restrict__ dst) {
  const int c0 = 2 * G4 * E_ / 8, c1 = c0 + 2 * G4 * H_ / 8,
            c2 = c1 + 2 * G4 * 1024 / 8, c3 = c2 + 2 * G4 * H_ / 8;
  int i8 = blockIdx.x * blockDim.x + threadIdx.x;
  int stride = gridDim.x * blockDim.x;
  for (; i8 < c3; i8 += stride) {
    const float* s; int o8;
    if (i8 < c0) { s = s0; o8 = i8; }
    else if (i8 < c1) { s = s1; o8 = i8 - c0; }
    else if (i8 < c2) { s = s2; o8 = i8 - c1; }
    else { s = s3; o8 = i8 - c2; }
    int o = o8 * 8;
    float4 x = *(const float4*)&s[o];
    float4 y = *(const float4*)&s[o + 4];
    i32x4 v = {(int)pk2(x.x, x.y), (int)pk2(x.z, x.w),
               (int)pk2(y.x, y.y), (int)pk2(y.z, y.w)};
    *(i32x4*)&dst[i8 * 8] = v;
  }
}

__global__ void k_f2bf(const float* __restrict__ in, unsigned short* __restrict__ out, int n) {
  int i = blockIdx.x * blockDim.x + threadIdx.x;
  int stride = gridDim.x * blockDim.x;
  for (; i < n; i += stride) out[i] = f2bf(in[i]);
}

__global__ void k_addbias(const float* __restrict__ a, const float* __restrict__ b,
                          float* __restrict__ out, int n) {
  int i = blockIdx.x * blockDim.x + threadIdx.x;
  if (i < n) out[i] = a[i] + b[i];
}

__global__ void k_gather(const int* __restrict__ Y, const float* __restrict__ emb,
                         unsigned short* __restrict__ X) {
  int sb = blockIdx.x;
  int t = sb >> 6, b = sb & 63;
  int idx = (t == 0) ? Y[b * S_ + 1] : Y[b * S_ + t - 1];
  const float* src = emb + (size_t)idx * E_;
  unsigned short* dst = X + (size_t)sb * E_;
  for (int e = threadIdx.x; e < E_; e += blockDim.x) dst[e] = f2bf(src[e]);
}

__global__ void k_init_h(const float* __restrict__ hid,
                         unsigned short* __restrict__ h0i, unsigned short* __restrict__ h1i) {
  int i = blockIdx.x * blockDim.x + threadIdx.x;
  if (i >= 4 * B_ * H_) return;
  unsigned short v = f2bf(hid[i]);
  if (i < 2 * B_ * H_) h0i[i] = v;
  else h1i[i - 2 * B_ * H_] = v;
}

// ---------------- G0 GEMM: bf16 into d_out row tails (R10-proven) ----------------
__global__ __launch_bounds__(256) void k_gemm_g0(
    const unsigned short* __restrict__ A, const unsigned short* __restrict__ B,
    const float* __restrict__ bias, unsigned short* __restrict__ C,
    int K, int nTM, int nwg) {
  __shared__ unsigned short Als[128 * 32];
  __shared__ unsigned short Bls[128 * 32];
  int tid = threadIdx.x;
  int o = blockIdx.x;
  int wg = (o & 7) * (nwg >> 3) + (o >> 3);
  int bm = wg % nTM, bn = wg / nTM;
  int w = tid >> 6, l = tid & 63;
  int wr = w >> 1, wc = w & 1;
  int lr = l & 15, hi = l >> 4;
  int c0 = w * 128 + l;
  int row0 = c0 >> 2, ks0 = (((c0 & 3) ^ (row0 & 3)) * 8);
  int c1 = c0 + 64;
  int row1 = c1 >> 2, ks1 = (((c1 & 3) ^ (row1 & 3)) * 8);
  const unsigned short* Ab = A + (size_t)(bm * 128) * K;
  const unsigned short* Bb = B + (size_t)(bn * 128) * K;
  unsigned short* AlsW = &Als[w * 1024];
  unsigned short* BlsW = &Bls[w * 1024];
  int co = ((hi ^ (lr & 3)) * 8);
  f32x4 acc[4][4] = {};
  for (int kk = 0; kk < K; kk += 32) {
    __syncthreads();
    gload_lds16(Ab + (size_t)row0 * K + kk + ks0, AlsW);
    gload_lds16(Ab + (size_t)row1 * K + kk + ks1, AlsW + 512);
    gload_lds16(Bb + (size_t)row0 * K + kk + ks0, BlsW);
    gload_lds16(Bb + (size_t)row1 * K + kk + ks1, BlsW + 512);
    __syncthreads();
    short8 af[4], bfr[4];
#pragma unroll
    for (int r = 0; r < 4; r++)
      af[r] = *(const short8*)&Als[(wr * 64 + r * 16 + lr) * 32 + co];
#pragma unroll
    for (int c4 = 0; c4 < 4; c4++)
      bfr[c4] = *(const short8*)&Bls[(wc * 64 + c4 * 16 + lr) * 32 + co];
#pragma unroll
    for (int r = 0; r < 4; r++)
#pragma unroll
      for (int c4 = 0; c4 < 4; c4++)
        acc[r][c4] = __builtin_amdgcn_mfma_f32_16x16x32_bf16(af[r], bfr[c4], acc[r][c4], 0, 0, 0);
  }
  int rbase = bm * 128 + wr * 64 + hi * 4;
  int cbase = bn * 128 + wc * 64 + lr;
#pragma unroll
  for (int r = 0; r < 4; r++) {
#pragma unroll
    for (int c4 = 0; c4 < 4; c4++) {
      int cc = cbase + c4 * 16;
      float bv = bias[cc];
#pragma unroll
      for (int j = 0; j < 4; j++) {
        int rr = rbase + r * 16 + j;
        C[(size_t)rr * OROW_US + GTAIL_US + cc] = f2bf(acc[r][c4][j] + bv);
      }
    }
  }
}

// ---------------- final GEMM: out[b*64+t, v] = O1 @ fcw^T + fcb (R15-proven) ----------------
__global__ __launch_bounds__(256) void k_gemm_fc(
    const unsigned short* __restrict__ A, const unsigned short* __restrict__ B,
    const float* __restrict__ bias, float* __restrict__ C,
    int N, int K, int nTM, int nwg) {
  __shared__ unsigned short Als[128 * 32];
  __shared__ unsigned short Bls[128 * 32];
  int tid = threadIdx.x;
  int o = blockIdx.x;
  int wg = (o & 7) * (nwg >> 3) + (o >> 3);   // bijective XCD swizzle (nwg%8==0)
  int bm = wg % nTM, bn = wg / nTM;           // bm-major
  int w = tid >> 6, l = tid & 63;
  int wr = w >> 1, wc = w & 1;
  int lr = l & 15, hi = l >> 4;
  int c0 = w * 128 + l;
  int row0 = c0 >> 2, ks0 = (((c0 & 3) ^ (row0 & 3)) * 8);
  int c1 = c0 + 64;
  int row1 = c1 >> 2, ks1 = (((c1 & 3) ^ (row1 & 3)) * 8);
  const unsigned short* Ab = A + (size_t)(bm * 128) * K;
  const unsigned short* Bb = B + (size_t)(bn * 128) * K;
  unsigned short* AlsW = &Als[w * 1024];
  unsigned short* BlsW = &Bls[w * 1024];
  int co = ((hi ^ (lr & 3)) * 8);
  f32x4 acc[4][4] = {};
  for (int kk = 0; kk < K; kk += 32) {
    __syncthreads();
    gload_lds16(Ab + (size_t)row0 * K + kk + ks0, AlsW);
    gload_lds16(Ab + (size_t)row1 * K + kk + ks1, AlsW + 512);
    gload_lds16(Bb + (size_t)row0 * K + kk + ks0, BlsW);
    gload_lds16(Bb + (size_t)row1 * K + kk + ks1, BlsW + 512);
    __syncthreads();
    short8 af[4], bfr[4];
#pragma unroll
    for (int r = 0; r < 4; r++)
      af[r] = *(const short8*)&Als[(wr * 64 + r * 16 + lr) * 32 + co];
#pragma unroll
    for (int c4 = 0; c4 < 4; c4++)
      bfr[c4] = *(const short8*)&Bls[(wc * 64 + c4 * 16 + lr) * 32 + co];
#pragma unroll
    for (int r = 0; r < 4; r++)
#pragma unroll
      for (int c4 = 0; c4 < 4; c4++)
        acc[r][c4] = __builtin_amdgcn_mfma_f32_16x16x32_bf16(af[r], bfr[c4], acc[r][c4], 0, 0, 0);
  }
  int rbase = bm * 128 + wr * 64 + hi * 4;
  int cbase = bn * 128 + wc * 64 + lr;
#pragma unroll
  for (int r = 0; r < 4; r++) {
#pragma unroll
    for (int c4 = 0; c4 < 4; c4++) {
      int cc = cbase + c4 * 16;
      float bv = bias[cc];
#pragma unroll
      for (int j = 0; j < 4; j++) {
        int rr = rbase + r * 16 + j;
        size_t orow = (size_t)((rr & 63) * 64 + (rr >> 6));   // (S,B)->(B,S) permute
        __builtin_nontemporal_store(acc[r][c4][j] + bv, &C[orow * (size_t)N + cc]);
      }
    }
  }
}

// ---------------- fused persistent LSTM: 64 blocks x 512 threads ----------------
// [0,32): layer 0 — d=blk>>4, jt=blk&15, 32 j-cols, whh0 (4g x 32j x 512K) in LDS,
//         G0 bf16 from d_out tails. 8 waves: bt=w>>1 (batch 16-tile), jc=w&1.
// [32,64): layer 1 — same shape; whh1 in LDS; wih1 from GLOBAL in the pipelined
//         x1 phase (off the recurrent chain, carried acc).
// Flags: cnt0[t][d] tgt 16 (H0[t,d] published), cnt1[t][d] tgt 16 (O1[t,d]).
// 512 threads/block doubles outstanding-miss parallelism on the per-step 64KB
// h broadcast fetch (the R15 chain decomposition's dominant term).
#define LDWr 520    // row pitch: 512 + 8 pad
#define NBLK 64

__global__ __launch_bounds__(512) void k_fused_lstm(
    const unsigned short* __restrict__ h0i,   // (2,B,H) bf16
    const unsigned short* __restrict__ h1i,   // (2,B,H) bf16
    const float* __restrict__ cell,           // (4,B,H) fp32 [l0f,l0b,l1f,l1b]
    const unsigned short* __restrict__ whh0,  // (2,2048,512) bf16
    const unsigned short* __restrict__ wih1,  // (2,2048,1024) bf16
    const unsigned short* __restrict__ whh1,  // (2,2048,512) bf16
    const float* __restrict__ b1s,            // (2,2048) fp32
    const unsigned short* __restrict__ G0u,   // d_out as ushort (bf16 G0 tails)
    unsigned short* __restrict__ H0,          // (SB,1024) bf16  layer-0 output
    unsigned short* __restrict__ O1,          // (SB,1024) bf16  layer-1 output
    unsigned* __restrict__ cnt0, unsigned* __restrict__ cnt1) {
  __shared__ unsigned short SM[128 * LDWr];             // 133,120 B
  __shared__ __align__(16) unsigned short HS[64 * 32];  // publish staging 4KB
  int tid = threadIdx.x;
  int w = tid >> 6, l = tid & 63;
  int lr = l & 15, hi = l >> 4;
  int bt = w >> 1, jc = w & 1;      // batch 16-tile, j-col 16-tile within 32

  bool isL0 = blockIdx.x < 32;
  int idx = isL0 ? blockIdx.x : blockIdx.x - 32;
  int d = idx >> 4, jt = idx & 15;
  int j0 = jt * 32;

  // stage whh: 128 rows = 4 gates x 32 j-cols, K=512
  {
    const unsigned short* Wd = (isL0 ? whh0 : whh1) + (size_t)d * (G4 * H_);
    for (int c = tid; c < 128 * 64; c += 512) {
      int row = c >> 6, ck = c & 63;
      int g = row >> 5, rr = row & 31;
      *(int4*)&SM[row * LDWr + ck * 8] =
          *(const int4*)&Wd[(size_t)(g * H_ + j0 + rr) * H_ + ck * 8];
    }
  }
  int j = j0 + jc * 16 + lr;
  int b0 = bt * 16 + hi * 4;
  f32x4 creg;
  {
    const float* cd = cell + (size_t)((isL0 ? 0 : 2) + d) * (B_ * H_);
#pragma unroll
    for (int jj = 0; jj < 4; jj++) creg[jj] = cd[(size_t)(b0 + jj) * H_ + j];
  }
  __syncthreads();

  if (isL0) {
    // ================= LAYER 0 =================
    float gv[4][4];
    auto preloadG = [&](int t) {
#pragma unroll
      for (int jj = 0; jj < 4; jj++) {
        const unsigned short* Gb =
            G0u + (size_t)(t * B_ + b0 + jj) * OROW_US + GTAIL_US + d * 2048 + j;
#pragma unroll
        for (int g = 0; g < 4; g++) gv[g][jj] = bf2f(Gb[g * 512]);
      }
    };
    preloadG(0);
    for (int t = 0; t < S_; ++t) {
      if (t >= 1) {
        if (tid == 0) spin_ge(&cnt0[CIDX(t - 1, d, 0)], 16);
        __syncthreads();
      }
      const unsigned short* hp = (t == 0) ? h0i + (size_t)d * (B_ * H_)
                                          : H0 + (size_t)(t - 1) * B_ * 1024 + d * 512;
      size_t hstr = (t == 0) ? (size_t)H_ : 1024;
      const unsigned short* arow = hp + (size_t)(bt * 16 + lr) * hstr + hi * 8;
      f32x4 acc[4] = {};
#pragma unroll
      for (int ki = 0; ki < 16; ki++) {
        short8 a = *(const short8*)&arow[ki * 32];
#pragma unroll
        for (int g = 0; g < 4; g++) {
          short8 bfr = *(const short8*)&SM[(g * 32 + jc * 16 + lr) * LDWr + ki * 32 + hi * 8];
          acc[g] = __builtin_amdgcn_mfma_f32_16x16x32_bf16(a, bfr, acc[g], 0, 0, 0);
        }
      }
#pragma unroll
      for (int jj = 0; jj < 4; jj++) {
        float gi = acc[0][jj] + gv[0][jj];
        float gf = acc[1][jj] + gv[1][jj];
        float gg = acc[2][jj] + gv[2][jj];
        float go = acc[3][jj] + gv[3][jj];
        float c = sigm(gf) * creg[jj] + sigm(gi) * tanhf(gg);
        creg[jj] = c;
        HS[(b0 + jj) * 32 + jc * 16 + lr] = f2bf(sigm(go) * tanhf(c));
      }
      __syncthreads();
      unsigned short* Ho = H0 + (size_t)t * B_ * 1024 + d * 512 + j0;
      if (tid < 256) {
        int r = tid >> 2, q = tid & 3;
        st128_sys(&Ho[(size_t)r * 1024 + q * 8], *(const i32x4*)&HS[r * 32 + q * 8]);
      }
      wait_vm0();
      __syncthreads();
      if (tid == 0) arrive(&cnt0[CIDX(t, d, 0)]);
      if (t + 1 < S_) preloadG(t + 1);
    }
  } else {
    // ================= LAYER 1 (pipelined x1 from global wih1) =================
    const float* b1d = b1s + d * G4;
    float bi_[4];
#pragma unroll
    for (int g = 0; g < 4; g++) bi_[g] = b1d[g * 512 + j];
    const unsigned short* Wg[4];
#pragma unroll
    for (int g = 0; g < 4; g++)
      Wg[g] = wih1 + (size_t)d * (G4 * 1024) +
              (size_t)(g * 512 + j0 + jc * 16 + lr) * 1024 + hi * 8;
    f32x4 acc[4];
    auto x1phase = [&](int t) {
      if (tid < 2) spin_ge(&cnt0[CIDX(t, tid, 0)], 16);
      __syncthreads();
#pragma unroll
      for (int g = 0; g < 4; g++) acc[g] = (f32x4){};
      const unsigned short* x1row = H0 + ((size_t)t * B_ + bt * 16 + lr) * 1024 + hi * 8;
#pragma unroll 4
      for (int ki = 0; ki < 32; ki++) {
        short8 a = *(const short8*)&x1row[ki * 32];
#pragma unroll
        for (int g = 0; g < 4; g++) {
          short8 bfr = *(const short8*)&Wg[g][ki * 32];
          acc[g] = __builtin_amdgcn_mfma_f32_16x16x32_bf16(a, bfr, acc[g], 0, 0, 0);
        }
      }
    };
    x1phase(0);
    for (int t = 0; t < S_; ++t) {
      if (t >= 1) {
        if (tid == 0) spin_ge(&cnt1[CIDX(t - 1, d, 0)], 16);
        __syncthreads();
      }
      const unsigned short* hprev = (t == 0)
          ? h1i + (size_t)d * (B_ * H_) + (size_t)(bt * 16 + lr) * H_ + hi * 8
          : O1 + ((size_t)(t - 1) * B_ + bt * 16 + lr) * 1024 + d * 512 + hi * 8;
#pragma unroll
      for (int ki = 0; ki < 16; ki++) {
        short8 a = *(const short8*)&hprev[ki * 32];
#pragma unroll
        for (int g = 0; g < 4; g++) {
          short8 bfr = *(const short8*)&SM[(g * 32 + jc * 16 + lr) * LDWr + ki * 32 + hi * 8];
          acc[g] = __builtin_amdgcn_mfma_f32_16x16x32_bf16(a, bfr, acc[g], 0, 0, 0);
        }
      }
#pragma unroll
      for (int jj = 0; jj < 4; jj++) {
        float gi = acc[0][jj] + bi_[0];
        float gf = acc[1][jj] + bi_[1];
        float gg = acc[2][jj] + bi_[2];
        float go = acc[3][jj] + bi_[3];
        float c = sigm(gf) * creg[jj] + sigm(gi) * tanhf(gg);
        creg[jj] = c;
        HS[(b0 + jj) * 32 + jc * 16 + lr] = f2bf(sigm(go) * tanhf(c));
      }
      __syncthreads();
      unsigned short* Oo = O1 + (size_t)t * B_ * 1024 + d * 512 + j0;
      if (tid < 256) {
        int r = tid >> 2, q = tid & 3;
        st128_sys(&Oo[(size_t)r * 1024 + q * 8], *(const i32x4*)&HS[r * 32 + q * 8]);
      }
      wait_vm0();
      __syncthreads();
      if (tid == 0 && t + 1 < S_) arrive(&cnt1[CIDX(t, d, 0)]);
      if (t + 1 < S_) x1phase(t + 1);
    }
  }
}

extern "C" void kernel_launch(void* const* d_in, const int* in_sizes, int n_in,
                              void* d_out, int out_size, void* d_ws, size_t ws_size,
                              hipStream_t stream) {
  const float* hidden = (const float*)d_in[0];
  const float* cell   = (const float*)d_in[1];
  const int*   Y      = (const int*)d_in[2];
  const float* emb    = (const float*)d_in[3];
  const float* wih0   = (const float*)d_in[4];
  const float* whh0   = (const float*)d_in[5];
  const float* bih0   = (const float*)d_in[6];
  const float* bhh0   = (const float*)d_in[7];
  const float* wih1   = (const float*)d_in[8];
  const float* whh1   = (const float*)d_in[9];
  const float* bih1   = (const float*)d_in[10];
  const float* bhh1   = (const float*)d_in[11];
  const float* fcw    = (const float*)d_in[12];
  const float* fcb    = (const float*)d_in[13];

  char* ws = (char*)d_ws;
  size_t off = 0;
  auto alloc = [&](size_t bytes) {
    void* p = ws + off;
    off += (bytes + 255) & ~(size_t)255;
    return p;
  };
  // the four LSTM weight buffers stay contiguous (k_f2bf4 writes them as one)
  unsigned short* wih0b = (unsigned short*)alloc((size_t)2 * G4 * E_ * 2);
  unsigned short* whh0b = (unsigned short*)alloc((size_t)2 * G4 * H_ * 2);
  unsigned short* wih1b = (unsigned short*)alloc((size_t)2 * G4 * 1024 * 2);
  unsigned short* whh1b = (unsigned short*)alloc((size_t)2 * G4 * H_ * 2);
  unsigned short* fcwb  = (unsigned short*)alloc((size_t)V_ * 1024 * 2);
  unsigned short* Xb    = (unsigned short*)alloc((size_t)SB * E_ * 2);
  unsigned short* H0    = (unsigned short*)alloc((size_t)SB * 1024 * 2);
  unsigned short* O1    = (unsigned short*)alloc((size_t)SB * 1024 * 2);
  unsigned short* h0i   = (unsigned short*)alloc((size_t)2 * B_ * H_ * 2);
  unsigned short* h1i   = (unsigned short*)alloc((size_t)2 * B_ * H_ * 2);
  float* b0s = (float*)alloc((size_t)2 * G4 * 4);
  float* b1s = (float*)alloc((size_t)2 * G4 * 4);
  unsigned* cnt0 = (unsigned*)alloc(CNT_BYTES);
  unsigned* cnt1 = (unsigned*)alloc(CNT_BYTES);
  (void)ws_size;

  // --- prep ---
  k_f2bf4<<<2048, 256, 0, stream>>>(wih0, whh0, wih1, whh1, wih0b);
  k_f2bf<<<4096, 256, 0, stream>>>(fcw, fcwb, V_ * 1024);
  k_addbias<<<16, 256, 0, stream>>>(bih0, bhh0, b0s, 2 * G4);
  k_addbias<<<16, 256, 0, stream>>>(bih1, bhh1, b1s, 2 * G4);
  k_gather<<<SB, 256, 0, stream>>>(Y, emb, Xb);
  k_init_h<<<512, 256, 0, stream>>>(hidden, h0i, h1i);
  (void)hipMemsetAsync(cnt0, 0, CNT_BYTES, stream);
  (void)hipMemsetAsync(cnt1, 0, CNT_BYTES, stream);

  // --- layer-0 input gates -> bf16 G0 in d_out row tails ---
  k_gemm_g0<<<1024, 256, 0, stream>>>(Xb, wih0b, b0s, (unsigned short*)d_out,
                                      E_, SB / 128, 1024);

  // --- fused persistent recurrence (64 blocks x 512 threads) ---
  k_fused_lstm<<<NBLK, 512, 0, stream>>>(h0i, h1i, cell, whh0b, wih1b, whh1b,
                                         b1s, (const unsigned short*)d_out,
                                         H0, O1, cnt0, cnt1);

  // --- final projection (after rec; overwrites G0 tails safely) ---
  k_gemm_fc<<<(SB / 128) * (V_ / 128), 256, 0, stream>>>(
      O1, fcwb, fcb, (float*)d_out, V_, 1024, SB / 128, (SB / 128) * (V_ / 128));
}

// Round 17
// 1180.186 us; speedup vs baseline: 2.6589x; 2.6589x over previous
//
#include <hip/hip_runtime.h>
#include <hip/hip_bf16.h>
#include <stdint.h>

#define S_ 64
#define B_ 64
#define E_ 512
#define H_ 512
#define V_ 32000
#define G4 2048   // 4*H
#define SB 4096   // S*B

// d_out row = 32000 fp32 = 64000 ushort; G0 (bf16) lives in the tail 4096
// ushorts of each row: G0(sb, d, c) at ushort index sb*64000 + 59904 + d*2048 + c.
// Sequential structure: final GEMM runs after rec and overwrites the tails.
#define OROW_US 64000
#define GTAIL_US 59904   // 29952 fp32 * 2

typedef __attribute__((ext_vector_type(8))) short short8;
typedef __attribute__((ext_vector_type(4))) float f32x4;
typedef __attribute__((ext_vector_type(4))) int i32x4;

static __device__ __forceinline__ unsigned short f2bf(float f) {
  unsigned u = __float_as_uint(f);
  u += 0x7fff + ((u >> 16) & 1);   // RNE
  return (unsigned short)(u >> 16);
}
static __device__ __forceinline__ unsigned pk2(float a, float b) {
  return (unsigned)f2bf(a) | ((unsigned)f2bf(b) << 16);
}
static __device__ __forceinline__ float bf2f(unsigned short u) {
  return __uint_as_float((unsigned)u << 16);
}
// fast gate activations via native v_exp_f32 (exp2)
static __device__ __forceinline__ float sigm(float x) {
  return 1.f / (1.f + exp2f(x * -1.44269504f));
}
static __device__ __forceinline__ float tanh_fast(float x) {
  float e = exp2f(x * 2.88539008f);   // e^(2x)
  return 1.f - 2.f / (e + 1.f);       // exact limits at +-inf
}

__device__ __forceinline__ void gload_lds16(const void* g, void* l) {
  __builtin_amdgcn_global_load_lds(
      (const __attribute__((address_space(1))) void*)g,
      (__attribute__((address_space(3))) void*)l, 16, 0, 0);
}

// coherent (device-visible) 16-byte store: write-through past the XCD L2
__device__ __forceinline__ void st128_sys(void* p, i32x4 v) {
  asm volatile("global_store_dwordx4 %0, %1, off sc0 sc1"
               :: "v"((unsigned long long)p), "v"(v) : "memory");
}
__device__ __forceinline__ void wait_vm0() {
  asm volatile("s_waitcnt vmcnt(0)" ::: "memory");
}

__device__ __forceinline__ void spin_ge(unsigned* c, unsigned tgt) {
  while (__hip_atomic_load(c, __ATOMIC_RELAXED, __HIP_MEMORY_SCOPE_AGENT) < tgt)
    __builtin_amdgcn_s_sleep(1);
}
__device__ __forceinline__ void arrive(unsigned* c) {
  __hip_atomic_fetch_add(c, 1u, __ATOMIC_RELAXED, __HIP_MEMORY_SCOPE_AGENT);
}

// fine-grain counter slot: per (step, dir, part), 256B apart (R8-proven)
#define CIDX(t, d, p) ((((t) * 8) + ((d) * 4) + (p)) * 64)
#define CNT_BYTES (64 * 8 * 64 * 4)

// ---- merged fp32->bf16 for the four LSTM weight tensors (contiguous dst) ----
__global__ void k_f2bf4(const float* __restrict__ s0, const float* __restrict__ s1,
                        const float* __restrict__ s2, const float* __restrict__ s3,
                        unsigned short* __restrict__ dst) {
  const int c0 = 2 * G4 * E_ / 8, c1 = c0 + 2 * G4 * H_ / 8,
            c2 = c1 + 2 * G4 * 1024 / 8, c3 = c2 + 2 * G4 * H_ / 8;
  int i8 = blockIdx.x * blockDim.x + threadIdx.x;
  int stride = gridDim.x * blockDim.x;
  for (; i8 < c3; i8 += stride) {
    const float* s; int o8;
    if (i8 < c0) { s = s0; o8 = i8; }
    else if (i8 < c1) { s = s1; o8 = i8 - c0; }
    else if (i8 < c2) { s = s2; o8 = i8 - c1; }
    else { s = s3; o8 = i8 - c2; }
    int o = o8 * 8;
    float4 x = *(const float4*)&s[o];
    float4 y = *(const float4*)&s[o + 4];
    i32x4 v = {(int)pk2(x.x, x.y), (int)pk2(x.z, x.w),
               (int)pk2(y.x, y.y), (int)pk2(y.z, y.w)};
    *(i32x4*)&dst[i8 * 8] = v;
  }
}

__global__ void k_f2bf(const float* __restrict__ in, unsigned short* __restrict__ out, int n) {
  int i = blockIdx.x * blockDim.x + threadIdx.x;
  int stride = gridDim.x * blockDim.x;
  for (; i < n; i += stride) out[i] = f2bf(in[i]);
}

__global__ void k_addbias(const float* __restrict__ a, const float* __restrict__ b,
                          float* __restrict__ out, int n) {
  int i = blockIdx.x * blockDim.x + threadIdx.x;
  if (i < n) out[i] = a[i] + b[i];
}

__global__ void k_gather(const int* __restrict__ Y, const float* __restrict__ emb,
                         unsigned short* __restrict__ X) {
  int sb = blockIdx.x;
  int t = sb >> 6, b = sb & 63;
  int idx = (t == 0) ? Y[b * S_ + 1] : Y[b * S_ + t - 1];
  const float* src = emb + (size_t)idx * E_;
  unsigned short* dst = X + (size_t)sb * E_;
  for (int e = threadIdx.x; e < E_; e += blockDim.x) dst[e] = f2bf(src[e]);
}

__global__ void k_init_h(const float* __restrict__ hid,
                         unsigned short* __restrict__ h0i, unsigned short* __restrict__ h1i) {
  int i = blockIdx.x * blockDim.x + threadIdx.x;
  if (i >= 4 * B_ * H_) return;
  unsigned short v = f2bf(hid[i]);
  if (i < 2 * B_ * H_) h0i[i] = v;
  else h1i[i - 2 * B_ * H_] = v;
}

// ---------------- G0 GEMM: bf16 into d_out row tails (R10-proven) ----------------
__global__ __launch_bounds__(256) void k_gemm_g0(
    const unsigned short* __restrict__ A, const unsigned short* __restrict__ B,
    const float* __restrict__ bias, unsigned short* __restrict__ C,
    int K, int nTM, int nwg) {
  __shared__ unsigned short Als[128 * 32];
  __shared__ unsigned short Bls[128 * 32];
  int tid = threadIdx.x;
  int o = blockIdx.x;
  int wg = (o & 7) * (nwg >> 3) + (o >> 3);
  int bm = wg % nTM, bn = wg / nTM;
  int w = tid >> 6, l = tid & 63;
  int wr = w >> 1, wc = w & 1;
  int lr = l & 15, hi = l >> 4;
  int c0 = w * 128 + l;
  int row0 = c0 >> 2, ks0 = (((c0 & 3) ^ (row0 & 3)) * 8);
  int c1 = c0 + 64;
  int row1 = c1 >> 2, ks1 = (((c1 & 3) ^ (row1 & 3)) * 8);
  const unsigned short* Ab = A + (size_t)(bm * 128) * K;
  const unsigned short* Bb = B + (size_t)(bn * 128) * K;
  unsigned short* AlsW = &Als[w * 1024];
  unsigned short* BlsW = &Bls[w * 1024];
  int co = ((hi ^ (lr & 3)) * 8);
  f32x4 acc[4][4] = {};
  for (int kk = 0; kk < K; kk += 32) {
    __syncthreads();
    gload_lds16(Ab + (size_t)row0 * K + kk + ks0, AlsW);
    gload_lds16(Ab + (size_t)row1 * K + kk + ks1, AlsW + 512);
    gload_lds16(Bb + (size_t)row0 * K + kk + ks0, BlsW);
    gload_lds16(Bb + (size_t)row1 * K + kk + ks1, BlsW + 512);
    __syncthreads();
    short8 af[4], bfr[4];
#pragma unroll
    for (int r = 0; r < 4; r++)
      af[r] = *(const short8*)&Als[(wr * 64 + r * 16 + lr) * 32 + co];
#pragma unroll
    for (int c4 = 0; c4 < 4; c4++)
      bfr[c4] = *(const short8*)&Bls[(wc * 64 + c4 * 16 + lr) * 32 + co];
#pragma unroll
    for (int r = 0; r < 4; r++)
#pragma unroll
      for (int c4 = 0; c4 < 4; c4++)
        acc[r][c4] = __builtin_amdgcn_mfma_f32_16x16x32_bf16(af[r], bfr[c4], acc[r][c4], 0, 0, 0);
  }
  int rbase = bm * 128 + wr * 64 + hi * 4;
  int cbase = bn * 128 + wc * 64 + lr;
#pragma unroll
  for (int r = 0; r < 4; r++) {
#pragma unroll
    for (int c4 = 0; c4 < 4; c4++) {
      int cc = cbase + c4 * 16;
      float bv = bias[cc];
#pragma unroll
      for (int j = 0; j < 4; j++) {
        int rr = rbase + r * 16 + j;
        C[(size_t)rr * OROW_US + GTAIL_US + cc] = f2bf(acc[r][c4][j] + bv);
      }
    }
  }
}

// ---------------- final GEMM: out[b*64+t, v] = O1 @ fcw^T + fcb (R15-proven) ----------------
__global__ __launch_bounds__(256) void k_gemm_fc(
    const unsigned short* __restrict__ A, const unsigned short* __restrict__ B,
    const float* __restrict__ bias, float* __restrict__ C,
    int N, int K, int nTM, int nwg) {
  __shared__ unsigned short Als[128 * 32];
  __shared__ unsigned short Bls[128 * 32];
  int tid = threadIdx.x;
  int o = blockIdx.x;
  int wg = (o & 7) * (nwg >> 3) + (o >> 3);   // bijective XCD swizzle (nwg%8==0)
  int bm = wg % nTM, bn = wg / nTM;           // bm-major
  int w = tid >> 6, l = tid & 63;
  int wr = w >> 1, wc = w & 1;
  int lr = l & 15, hi = l >> 4;
  int c0 = w * 128 + l;
  int row0 = c0 >> 2, ks0 = (((c0 & 3) ^ (row0 & 3)) * 8);
  int c1 = c0 + 64;
  int row1 = c1 >> 2, ks1 = (((c1 & 3) ^ (row1 & 3)) * 8);
  const unsigned short* Ab = A + (size_t)(bm * 128) * K;
  const unsigned short* Bb = B + (size_t)(bn * 128) * K;
  unsigned short* AlsW = &Als[w * 1024];
  unsigned short* BlsW = &Bls[w * 1024];
  int co = ((hi ^ (lr & 3)) * 8);
  f32x4 acc[4][4] = {};
  for (int kk = 0; kk < K; kk += 32) {
    __syncthreads();
    gload_lds16(Ab + (size_t)row0 * K + kk + ks0, AlsW);
    gload_lds16(Ab + (size_t)row1 * K + kk + ks1, AlsW + 512);
    gload_lds16(Bb + (size_t)row0 * K + kk + ks0, BlsW);
    gload_lds16(Bb + (size_t)row1 * K + kk + ks1, BlsW + 512);
    __syncthreads();
    short8 af[4], bfr[4];
#pragma unroll
    for (int r = 0; r < 4; r++)
      af[r] = *(const short8*)&Als[(wr * 64 + r * 16 + lr) * 32 + co];
#pragma unroll
    for (int c4 = 0; c4 < 4; c4++)
      bfr[c4] = *(const short8*)&Bls[(wc * 64 + c4 * 16 + lr) * 32 + co];
#pragma unroll
    for (int r = 0; r < 4; r++)
#pragma unroll
      for (int c4 = 0; c4 < 4; c4++)
        acc[r][c4] = __builtin_amdgcn_mfma_f32_16x16x32_bf16(af[r], bfr[c4], acc[r][c4], 0, 0, 0);
  }
  int rbase = bm * 128 + wr * 64 + hi * 4;
  int cbase = bn * 128 + wc * 64 + lr;
#pragma unroll
  for (int r = 0; r < 4; r++) {
#pragma unroll
    for (int c4 = 0; c4 < 4; c4++) {
      int cc = cbase + c4 * 16;
      float bv = bias[cc];
#pragma unroll
      for (int j = 0; j < 4; j++) {
        int rr = rbase + r * 16 + j;
        size_t orow = (size_t)((rr & 63) * 64 + (rr >> 6));   // (S,B)->(B,S) permute
        __builtin_nontemporal_store(acc[r][c4][j] + bv, &C[orow * (size_t)N + cc]);
      }
    }
  }
}

// ---------------- fused persistent 2-layer bidirectional LSTM (R15-proven) ----------------
// 192 blocks: [0,64): layer 0 (d=blk>>5, jt=blk&31, 16 j-cols, whh0 in LDS,
// G0 bf16 from d_out tails); [64,192): layer 1 (idx=blk-64, d=idx>>6, jt8=idx&63,
// 8 j-cols, packed wih1+whh1 in LDS, x1 phase pipelined off the chain).
//   cnt0[t][d][p] (tgt 8): H0[t] dir-d part-p published
//   cnt1[t][d][p] (tgt 16): O1[t] dir-d part-p published
#define LDW0 520    // l0: 64 rows x (512+8)
#define LDW1 1544   // l1: 32 rows x (1536+8)
#define NBLK 192

__global__ __launch_bounds__(256) void k_fused_lstm(
    const unsigned short* __restrict__ h0i,   // (2,B,H) bf16
    const unsigned short* __restrict__ h1i,   // (2,B,H) bf16
    const float* __restrict__ cell,           // (4,B,H) fp32 [l0f,l0b,l1f,l1b]
    const unsigned short* __restrict__ whh0,  // (2,2048,512) bf16
    const unsigned short* __restrict__ wih1,  // (2,2048,1024) bf16
    const unsigned short* __restrict__ whh1,  // (2,2048,512) bf16
    const float* __restrict__ b1s,            // (2,2048) fp32
    const unsigned short* __restrict__ G0u,   // d_out as ushort (bf16 G0 tails)
    unsigned short* __restrict__ H0,          // (SB,1024) bf16  layer-0 output
    unsigned short* __restrict__ O1,          // (SB,1024) bf16  layer-1 output
    unsigned* __restrict__ cnt0, unsigned* __restrict__ cnt1) {
  __shared__ unsigned short SM[32 * LDW1];    // 98,816 B (l0 uses 66,560 of it)
  __shared__ __align__(16) unsigned short HS[64 * 16];  // publish staging
  int tid = threadIdx.x;
  int w = tid >> 6, l = tid & 63;
  int lr = l & 15, hi = l >> 4;

  if (blockIdx.x < 64) {
    // ================= LAYER 0 =================
    int d = blockIdx.x >> 5, jt = blockIdx.x & 31;
    const unsigned short* Wd = whh0 + (size_t)d * (G4 * H_);
    for (int c = tid; c < 64 * 64; c += 256) {
      int row = c >> 6, ck = c & 63;
      int g = row >> 4, r16 = row & 15;
      *(int4*)&SM[row * LDW0 + ck * 8] =
          *(const int4*)&Wd[(size_t)(g * H_ + jt * 16 + r16) * H_ + ck * 8];
    }
    int j = jt * 16 + lr;
    int b0 = w * 16 + hi * 4;
    f32x4 creg;
    {
      const float* cd = cell + (size_t)d * (B_ * H_);
#pragma unroll
      for (int jj = 0; jj < 4; jj++) creg[jj] = cd[(size_t)(b0 + jj) * H_ + j];
    }
    __syncthreads();
    float gv[4][4];
    auto preloadG = [&](int t) {
#pragma unroll
      for (int jj = 0; jj < 4; jj++) {
        const unsigned short* Gb =
            G0u + (size_t)(t * B_ + b0 + jj) * OROW_US + GTAIL_US + d * 2048 + j;
#pragma unroll
        for (int g = 0; g < 4; g++) gv[g][jj] = bf2f(Gb[g * 512]);
      }
    };
    preloadG(0);
    for (int t = 0; t < S_; ++t) {
      if (t >= 1) {
        if (tid < 4) spin_ge(&cnt0[CIDX(t - 1, d, tid)], 8);
        __syncthreads();
      }
      const unsigned short* hp = (t == 0) ? h0i + (size_t)d * (B_ * H_)
                                          : H0 + (size_t)(t - 1) * B_ * 1024 + d * 512;
      size_t hstr = (t == 0) ? (size_t)H_ : 1024;
      const unsigned short* arow = hp + (size_t)(w * 16 + lr) * hstr + hi * 8;
      f32x4 acc[4] = {};
#pragma unroll
      for (int ki = 0; ki < 16; ki++) {
        short8 a = *(const short8*)&arow[ki * 32];
#pragma unroll
        for (int g = 0; g < 4; g++) {
          short8 bfr = *(const short8*)&SM[(g * 16 + lr) * LDW0 + ki * 32 + hi * 8];
          acc[g] = __builtin_amdgcn_mfma_f32_16x16x32_bf16(a, bfr, acc[g], 0, 0, 0);
        }
      }
#pragma unroll
      for (int jj = 0; jj < 4; jj++) {
        float gi = acc[0][jj] + gv[0][jj];
        float gf = acc[1][jj] + gv[1][jj];
        float gg = acc[2][jj] + gv[2][jj];
        float go = acc[3][jj] + gv[3][jj];
        float c = sigm(gf) * creg[jj] + sigm(gi) * tanh_fast(gg);
        creg[jj] = c;
        HS[(b0 + jj) * 16 + lr] = f2bf(sigm(go) * tanh_fast(c));
      }
      __syncthreads();
      unsigned short* Ho = H0 + (size_t)t * B_ * 1024 + d * 512 + jt * 16;
      if (tid < 128) {
        int r = tid >> 1, half = tid & 1;
        st128_sys(&Ho[(size_t)r * 1024 + half * 8], *(const i32x4*)&HS[r * 16 + half * 8]);
      }
      wait_vm0();
      __syncthreads();
      if (tid == 0) arrive(&cnt0[CIDX(t, d, jt & 3)]);
      if (t + 1 < S_) preloadG(t + 1);
    }
  } else {
    // ================= LAYER 1 (pipelined) =================
    int idx = blockIdx.x - 64;
    int d = idx >> 6, jt8 = idx & 63;
    int j0 = jt8 * 8;
    {
      const unsigned short* Wih = wih1 + (size_t)d * (G4 * 1024);
      const unsigned short* Whh = whh1 + (size_t)d * (G4 * H_);
      for (int c = tid; c < 32 * 192; c += 256) {
        int r = c / 192, ck = c - r * 192;
        int g = r >> 3, jc = r & 7;
        const unsigned short* src =
            (ck < 128) ? Wih + (size_t)(g * H_ + j0 + jc) * 1024 + ck * 8
                       : Whh + (size_t)(g * H_ + j0 + jc) * H_ + (ck - 128) * 8;
        *(int4*)&SM[r * LDW1 + ck * 8] = *(const int4*)src;
      }
    }
    int j = j0 + (lr & 7);
    const float* b1d = b1s + d * G4;
    float bi_ = b1d[j], bf_ = b1d[512 + j], bg_ = b1d[1024 + j], bo_ = b1d[1536 + j];
    int b0 = w * 16 + hi * 4;
    f32x4 creg = {};
    if (lr < 8) {
      const float* cd = cell + (size_t)(2 + d) * (B_ * H_);
#pragma unroll
      for (int jj = 0; jj < 4; jj++) creg[jj] = cd[(size_t)(b0 + jj) * H_ + j];
    }
    __syncthreads();

    f32x4 acc0, acc1;   // carry wih-part across the iteration boundary
    {
      if (tid < 8) spin_ge(&cnt0[CIDX(0, 0, 0) + tid * 64], 8);
      __syncthreads();
      acc0 = (f32x4){}; acc1 = (f32x4){};
      const unsigned short* x1row = H0 + ((size_t)0 * B_ + w * 16 + lr) * 1024 + hi * 8;
#pragma unroll 8
      for (int ki = 0; ki < 32; ki++) {
        short8 a = *(const short8*)&x1row[ki * 32];
        short8 bA = *(const short8*)&SM[(size_t)lr * LDW1 + ki * 32 + hi * 8];
        short8 bB = *(const short8*)&SM[(size_t)(16 + lr) * LDW1 + ki * 32 + hi * 8];
        acc0 = __builtin_amdgcn_mfma_f32_16x16x32_bf16(a, bA, acc0, 0, 0, 0);
        acc1 = __builtin_amdgcn_mfma_f32_16x16x32_bf16(a, bB, acc1, 0, 0, 0);
      }
    }
    for (int t = 0; t < S_; ++t) {
      if (t >= 1) {
        if (tid < 4) spin_ge(&cnt1[CIDX(t - 1, d, tid)], 16);
        __syncthreads();
      }
      const unsigned short* hprev = (t == 0)
          ? h1i + (size_t)d * (B_ * H_) + (size_t)(w * 16 + lr) * H_ + hi * 8
          : O1 + ((size_t)(t - 1) * B_ + w * 16 + lr) * 1024 + d * 512 + hi * 8;
#pragma unroll 8
      for (int ki = 0; ki < 16; ki++) {
        short8 a = *(const short8*)&hprev[ki * 32];
        short8 bA = *(const short8*)&SM[(size_t)lr * LDW1 + 1024 + ki * 32 + hi * 8];
        short8 bB = *(const short8*)&SM[(size_t)(16 + lr) * LDW1 + 1024 + ki * 32 + hi * 8];
        acc0 = __builtin_amdgcn_mfma_f32_16x16x32_bf16(a, bA, acc0, 0, 0, 0);
        acc1 = __builtin_amdgcn_mfma_f32_16x16x32_bf16(a, bB, acc1, 0, 0, 0);
      }
      float pf[4], po[4];
#pragma unroll
      for (int jj = 0; jj < 4; jj++) {
        pf[jj] = __shfl_xor(acc0[jj], 8);
        po[jj] = __shfl_xor(acc1[jj], 8);
      }
      if (lr < 8) {
#pragma unroll
        for (int jj = 0; jj < 4; jj++) {
          float gi = acc0[jj] + bi_;
          float gf = pf[jj] + bf_;
          float gg = acc1[jj] + bg_;
          float go = po[jj] + bo_;
          float c = sigm(gf) * creg[jj] + sigm(gi) * tanh_fast(gg);
          creg[jj] = c;
          HS[(b0 + jj) * 8 + lr] = f2bf(sigm(go) * tanh_fast(c));
        }
      }
      __syncthreads();
      unsigned short* Oo = O1 + (size_t)t * B_ * 1024 + d * 512 + j0;
      if (tid < 64) st128_sys(&Oo[(size_t)tid * 1024], *(const i32x4*)&HS[tid * 8]);
      wait_vm0();
      __syncthreads();
      if (tid == 0 && t + 1 < S_) arrive(&cnt1[CIDX(t, d, jt8 & 3)]);
      // tail: x1 phase for t+1 (overlaps peers' publish + flag propagation)
      if (t + 1 < S_) {
        if (tid < 8) spin_ge(&cnt0[CIDX(t + 1, 0, 0) + tid * 64], 8);
        __syncthreads();
        acc0 = (f32x4){}; acc1 = (f32x4){};
        const unsigned short* x1row =
            H0 + ((size_t)(t + 1) * B_ + w * 16 + lr) * 1024 + hi * 8;
#pragma unroll 8
        for (int ki = 0; ki < 32; ki++) {
          short8 a = *(const short8*)&x1row[ki * 32];
          short8 bA = *(const short8*)&SM[(size_t)lr * LDW1 + ki * 32 + hi * 8];
          short8 bB = *(const short8*)&SM[(size_t)(16 + lr) * LDW1 + ki * 32 + hi * 8];
          acc0 = __builtin_amdgcn_mfma_f32_16x16x32_bf16(a, bA, acc0, 0, 0, 0);
          acc1 = __builtin_amdgcn_mfma_f32_16x16x32_bf16(a, bB, acc1, 0, 0, 0);
        }
      }
    }
  }
}

extern "C" void kernel_launch(void* const* d_in, const int* in_sizes, int n_in,
                              void* d_out, int out_size, void* d_ws, size_t ws_size,
                              hipStream_t stream) {
  const float* hidden = (const float*)d_in[0];
  const float* cell   = (const float*)d_in[1];
  const int*   Y      = (const int*)d_in[2];
  const float* emb    = (const float*)d_in[3];
  const float* wih0   = (const float*)d_in[4];
  const float* whh0   = (const float*)d_in[5];
  const float* bih0   = (const float*)d_in[6];
  const float* bhh0   = (const float*)d_in[7];
  const float* wih1   = (const float*)d_in[8];
  const float* whh1   = (const float*)d_in[9];
  const float* bih1   = (const float*)d_in[10];
  const float* bhh1   = (const float*)d_in[11];
  const float* fcw    = (const float*)d_in[12];
  const float* fcb    = (const float*)d_in[13];

  char* ws = (char*)d_ws;
  size_t off = 0;
  auto alloc = [&](size_t bytes) {
    void* p = ws + off;
    off += (bytes + 255) & ~(size_t)255;
    return p;
  };
  // the four LSTM weight buffers stay contiguous (k_f2bf4 writes them as one)
  unsigned short* wih0b = (unsigned short*)alloc((size_t)2 * G4 * E_ * 2);
  unsigned short* whh0b = (unsigned short*)alloc((size_t)2 * G4 * H_ * 2);
  unsigned short* wih1b = (unsigned short*)alloc((size_t)2 * G4 * 1024 * 2);
  unsigned short* whh1b = (unsigned short*)alloc((size_t)2 * G4 * H_ * 2);
  unsigned short* fcwb  = (unsigned short*)alloc((size_t)V_ * 1024 * 2);
  unsigned short* Xb    = (unsigned short*)alloc((size_t)SB * E_ * 2);
  unsigned short* H0    = (unsigned short*)alloc((size_t)SB * 1024 * 2);
  unsigned short* O1    = (unsigned short*)alloc((size_t)SB * 1024 * 2);
  unsigned short* h0i   = (unsigned short*)alloc((size_t)2 * B_ * H_ * 2);
  unsigned short* h1i   = (unsigned short*)alloc((size_t)2 * B_ * H_ * 2);
  float* b0s = (float*)alloc((size_t)2 * G4 * 4);
  float* b1s = (float*)alloc((size_t)2 * G4 * 4);
  unsigned* cnt0 = (unsigned*)alloc(CNT_BYTES);
  unsigned* cnt1 = (unsigned*)alloc(CNT_BYTES);
  (void)ws_size;

  // --- prep ---
  k_f2bf4<<<2048, 256, 0, stream>>>(wih0, whh0, wih1, whh1, wih0b);
  k_f2bf<<<4096, 256, 0, stream>>>(fcw, fcwb, V_ * 1024);
  k_addbias<<<16, 256, 0, stream>>>(bih0, bhh0, b0s, 2 * G4);
  k_addbias<<<16, 256, 0, stream>>>(bih1, bhh1, b1s, 2 * G4);
  k_gather<<<SB, 256, 0, stream>>>(Y, emb, Xb);
  k_init_h<<<512, 256, 0, stream>>>(hidden, h0i, h1i);
  (void)hipMemsetAsync(cnt0, 0, CNT_BYTES, stream);
  (void)hipMemsetAsync(cnt1, 0, CNT_BYTES, stream);

  // --- layer-0 input gates -> bf16 G0 in d_out row tails ---
  k_gemm_g0<<<1024, 256, 0, stream>>>(Xb, wih0b, b0s, (unsigned short*)d_out,
                                      E_, SB / 128, 1024);

  // --- fused persistent recurrence (self-timed chains, R15 structure) ---
  k_fused_lstm<<<NBLK, 256, 0, stream>>>(h0i, h1i, cell, whh0b, wih1b, whh1b,
                                         b1s, (const unsigned short*)d_out,
                                         H0, O1, cnt0, cnt1);

  // --- final projection (after rec; overwrites G0 tails safely) ---
  k_gemm_fc<<<(SB / 128) * (V_ / 128), 256, 0, stream>>>(
      O1, fcwb, fcb, (float*)d_out, V_, 1024, SB / 128, (SB / 128) * (V_ / 128));
}

// Round 18
// 1103.654 us; speedup vs baseline: 2.8433x; 1.0693x over previous
//
#include <hip/hip_runtime.h>
#include <hip/hip_bf16.h>
#include <stdint.h>

#define S_ 64
#define B_ 64
#define E_ 512
#define H_ 512
#define V_ 32000
#define G4 2048   // 4*H
#define SB 4096   // S*B

// d_out row = 32000 fp32 = 64000 ushort; G0 (bf16) lives in the tail 4096
// ushorts of each row. Sequential: final GEMM overwrites tails after rec.
#define OROW_US 64000
#define GTAIL_US 59904   // 29952 fp32 * 2

typedef __attribute__((ext_vector_type(8))) short short8;
typedef __attribute__((ext_vector_type(4))) float f32x4;
typedef __attribute__((ext_vector_type(4))) int i32x4;

static __device__ __forceinline__ unsigned short f2bf(float f) {
  unsigned u = __float_as_uint(f);
  u += 0x7fff + ((u >> 16) & 1);   // RNE
  return (unsigned short)(u >> 16);
}
static __device__ __forceinline__ unsigned pk2(float a, float b) {
  return (unsigned)f2bf(a) | ((unsigned)f2bf(b) << 16);
}
static __device__ __forceinline__ float bf2f(unsigned short u) {
  return __uint_as_float((unsigned)u << 16);
}
// fast gate activations via native v_exp_f32 (exp2)
static __device__ __forceinline__ float sigm(float x) {
  return 1.f / (1.f + exp2f(x * -1.44269504f));
}
static __device__ __forceinline__ float tanh_fast(float x) {
  float e = exp2f(x * 2.88539008f);   // e^(2x)
  return 1.f - 2.f / (e + 1.f);
}

__device__ __forceinline__ void gload_lds16(const void* g, void* l) {
  __builtin_amdgcn_global_load_lds(
      (const __attribute__((address_space(1))) void*)g,
      (__attribute__((address_space(3))) void*)l, 16, 0, 0);
}

// coherent (device-visible) 16-byte store: write-through past the XCD L2
__device__ __forceinline__ void st128_sys(void* p, i32x4 v) {
  asm volatile("global_store_dwordx4 %0, %1, off sc0 sc1"
               :: "v"((unsigned long long)p), "v"(v) : "memory");
}
__device__ __forceinline__ void wait_vm0() {
  asm volatile("s_waitcnt vmcnt(0)" ::: "memory");
}

__device__ __forceinline__ void spin_ge(unsigned* c, unsigned tgt) {
  while (__hip_atomic_load(c, __ATOMIC_RELAXED, __HIP_MEMORY_SCOPE_AGENT) < tgt)
    __builtin_amdgcn_s_sleep(1);
}
__device__ __forceinline__ void arrive(unsigned* c) {
  __hip_atomic_fetch_add(c, 1u, __ATOMIC_RELAXED, __HIP_MEMORY_SCOPE_AGENT);
}

#define CIDX(t, d, p) ((((t) * 8) + ((d) * 4) + (p)) * 64)
#define CNT_BYTES (64 * 8 * 64 * 4)

__global__ void k_f2bf4(const float* __restrict__ s0, const float* __restrict__ s1,
                        const float* __restrict__ s2, const float* __restrict__ s3,
                        unsigned short* __restrict__ dst) {
  const int c0 = 2 * G4 * E_ / 8, c1 = c0 + 2 * G4 * H_ / 8,
            c2 = c1 + 2 * G4 * 1024 / 8, c3 = c2 + 2 * G4 * H_ / 8;
  int i8 = blockIdx.x * blockDim.x + threadIdx.x;
  int stride = gridDim.x * blockDim.x;
  for (; i8 < c3; i8 += stride) {
    const float* s; int o8;
    if (i8 < c0) { s = s0; o8 = i8; }
    else if (i8 < c1) { s = s1; o8 = i8 - c0; }
    else if (i8 < c2) { s = s2; o8 = i8 - c1; }
    else { s = s3; o8 = i8 - c2; }
    int o = o8 * 8;
    float4 x = *(const float4*)&s[o];
    float4 y = *(const float4*)&s[o + 4];
    i32x4 v = {(int)pk2(x.x, x.y), (int)pk2(x.z, x.w),
               (int)pk2(y.x, y.y), (int)pk2(y.z, y.w)};
    *(i32x4*)&dst[i8 * 8] = v;
  }
}

__global__ void k_f2bf(const float* __restrict__ in, unsigned short* __restrict__ out, int n) {
  int i = blockIdx.x * blockDim.x + threadIdx.x;
  int stride = gridDim.x * blockDim.x;
  for (; i < n; i += stride) out[i] = f2bf(in[i]);
}

__global__ void k_addbias(const float* __restrict__ a, const float* __restrict__ b,
                          float* __restrict__ out, int n) {
  int i = blockIdx.x * blockDim.x + threadIdx.x;
  if (i < n) out[i] = a[i] + b[i];
}

__global__ void k_gather(const int* __restrict__ Y, const float* __restrict__ emb,
                         unsigned short* __restrict__ X) {
  int sb = blockIdx.x;
  int t = sb >> 6, b = sb & 63;
  int idx = (t == 0) ? Y[b * S_ + 1] : Y[b * S_ + t - 1];
  const float* src = emb + (size_t)idx * E_;
  unsigned short* dst = X + (size_t)sb * E_;
  for (int e = threadIdx.x; e < E_; e += blockDim.x) dst[e] = f2bf(src[e]);
}

__global__ void k_init_h(const float* __restrict__ hid,
                         unsigned short* __restrict__ h0i, unsigned short* __restrict__ h1i) {
  int i = blockIdx.x * blockDim.x + threadIdx.x;
  if (i >= 4 * B_ * H_) return;
  unsigned short v = f2bf(hid[i]);
  if (i < 2 * B_ * H_) h0i[i] = v;
  else h1i[i - 2 * B_ * H_] = v;
}

// ---------------- G0 GEMM: bf16 into d_out row tails (R10-proven) ----------------
__global__ __launch_bounds__(256) void k_gemm_g0(
    const unsigned short* __restrict__ A, const unsigned short* __restrict__ B,
    const float* __restrict__ bias, unsigned short* __restrict__ C,
    int K, int nTM, int nwg) {
  __shared__ unsigned short Als[128 * 32];
  __shared__ unsigned short Bls[128 * 32];
  int tid = threadIdx.x;
  int o = blockIdx.x;
  int wg = (o & 7) * (nwg >> 3) + (o >> 3);
  int bm = wg % nTM, bn = wg / nTM;
  int w = tid >> 6, l = tid & 63;
  int wr = w >> 1, wc = w & 1;
  int lr = l & 15, hi = l >> 4;
  int c0 = w * 128 + l;
  int row0 = c0 >> 2, ks0 = (((c0 & 3) ^ (row0 & 3)) * 8);
  int c1 = c0 + 64;
  int row1 = c1 >> 2, ks1 = (((c1 & 3) ^ (row1 & 3)) * 8);
  const unsigned short* Ab = A + (size_t)(bm * 128) * K;
  const unsigned short* Bb = B + (size_t)(bn * 128) * K;
  unsigned short* AlsW = &Als[w * 1024];
  unsigned short* BlsW = &Bls[w * 1024];
  int co = ((hi ^ (lr & 3)) * 8);
  f32x4 acc[4][4] = {};
  for (int kk = 0; kk < K; kk += 32) {
    __syncthreads();
    gload_lds16(Ab + (size_t)row0 * K + kk + ks0, AlsW);
    gload_lds16(Ab + (size_t)row1 * K + kk + ks1, AlsW + 512);
    gload_lds16(Bb + (size_t)row0 * K + kk + ks0, BlsW);
    gload_lds16(Bb + (size_t)row1 * K + kk + ks1, BlsW + 512);
    __syncthreads();
    short8 af[4], bfr[4];
#pragma unroll
    for (int r = 0; r < 4; r++)
      af[r] = *(const short8*)&Als[(wr * 64 + r * 16 + lr) * 32 + co];
#pragma unroll
    for (int c4 = 0; c4 < 4; c4++)
      bfr[c4] = *(const short8*)&Bls[(wc * 64 + c4 * 16 + lr) * 32 + co];
#pragma unroll
    for (int r = 0; r < 4; r++)
#pragma unroll
      for (int c4 = 0; c4 < 4; c4++)
        acc[r][c4] = __builtin_amdgcn_mfma_f32_16x16x32_bf16(af[r], bfr[c4], acc[r][c4], 0, 0, 0);
  }
  int rbase = bm * 128 + wr * 64 + hi * 4;
  int cbase = bn * 128 + wc * 64 + lr;
#pragma unroll
  for (int r = 0; r < 4; r++) {
#pragma unroll
    for (int c4 = 0; c4 < 4; c4++) {
      int cc = cbase + c4 * 16;
      float bv = bias[cc];
#pragma unroll
      for (int j = 0; j < 4; j++) {
        int rr = rbase + r * 16 + j;
        C[(size_t)rr * OROW_US + GTAIL_US + cc] = f2bf(acc[r][c4][j] + bv);
      }
    }
  }
}

// ------- final GEMM: 256x256 tile, BK=64, counted-vmcnt pipeline (T2+T3+T4+T5) -------
// 512 threads = 8 waves (2M x 4N); per-wave C = 128x64 (acc[8][4]).
// LDS 128KB: 2 K-tile slots x (A 32KB + B 32KB). Stage via global_load_lds with
// 8-chunk XOR swizzle (chunk ^= row&7; pre-swizzled source + swizzled ds_read).
// Steady state: s_waitcnt vmcnt(8) (next tile stays in flight across barriers);
// stage(t+2) issued only after the read-ending barrier (no LDS landing clobber).
__global__ __launch_bounds__(512, 1) void k_gemm_fc256(
    const unsigned short* __restrict__ A,   // O1 (4096,1024) bf16
    const unsigned short* __restrict__ B,   // fcwb (32000,1024) bf16
    const float* __restrict__ bias, float* __restrict__ C) {
  __shared__ unsigned short LB[65536];      // 131072 B
  int tid = threadIdx.x;
  int w = tid >> 6, l = tid & 63;
  int lr = l & 15, hi = l >> 4;
  int wm = w >> 2, wn = w & 3;
  int o = blockIdx.x;
  int wg = (o & 7) * 250 + (o >> 3);        // bijective XCD swizzle (2000%8==0)
  int bm = wg & 15, bn = wg >> 4;           // bm-major (16 wgs share a B panel)
  const unsigned short* Ab = A + (size_t)(bm * 256) * 1024;
  const unsigned short* Bb = B + (size_t)(bn * 256) * 1024;
  int srcoff[4], cb[4];
#pragma unroll
  for (int r = 0; r < 4; r++) {
    int c = r * 512 + tid;
    int row = c >> 3, stc = c & 7;
    srcoff[r] = row * 1024 + (stc ^ (row & 7)) * 8;
    cb[r] = (r * 512 + w * 64) * 8;         // wave-uniform LDS elem base
  }
  auto stage = [&](int kt) {
    int slot = (kt & 1) * 32768;
#pragma unroll
    for (int r = 0; r < 4; r++)
      gload_lds16(Ab + srcoff[r] + kt * 64, &LB[slot + cb[r]]);
#pragma unroll
    for (int r = 0; r < 4; r++)
      gload_lds16(Bb + srcoff[r] + kt * 64, &LB[slot + 16384 + cb[r]]);
  };
  f32x4 acc[8][4] = {};
  stage(0);
  stage(1);
  for (int t = 0; t < 16; ++t) {
    if (t < 15) asm volatile("s_waitcnt vmcnt(8)" ::: "memory");
    else        asm volatile("s_waitcnt vmcnt(0)" ::: "memory");
    __builtin_amdgcn_s_barrier();
    __builtin_amdgcn_sched_barrier(0);
    const unsigned short* bufA = &LB[(t & 1) * 32768];
    const unsigned short* bufB = bufA + 16384;
    __builtin_amdgcn_s_setprio(1);
#pragma unroll
    for (int kh = 0; kh < 2; kh++) {
      short8 af[8], bf[4];
      int ch = ((kh * 4 + hi) ^ (lr & 7)) * 8;
#pragma unroll
      for (int mf = 0; mf < 8; mf++)
        af[mf] = *(const short8*)&bufA[(wm * 128 + mf * 16 + lr) * 64 + ch];
#pragma unroll
      for (int nf = 0; nf < 4; nf++)
        bf[nf] = *(const short8*)&bufB[(wn * 64 + nf * 16 + lr) * 64 + ch];
#pragma unroll
      for (int mf = 0; mf < 8; mf++)
#pragma unroll
        for (int nf = 0; nf < 4; nf++)
          acc[mf][nf] = __builtin_amdgcn_mfma_f32_16x16x32_bf16(af[mf], bf[nf], acc[mf][nf], 0, 0, 0);
    }
    __builtin_amdgcn_s_setprio(0);
    __builtin_amdgcn_sched_barrier(0);
    __builtin_amdgcn_s_barrier();
    if (t + 2 < 16) stage(t + 2);
  }
#pragma unroll
  for (int mf = 0; mf < 8; mf++) {
#pragma unroll
    for (int nf = 0; nf < 4; nf++) {
      int cc = bn * 256 + wn * 64 + nf * 16 + lr;
      float bv = bias[cc];
#pragma unroll
      for (int j = 0; j < 4; j++) {
        int rr = bm * 256 + wm * 128 + mf * 16 + hi * 4 + j;
        size_t orow = (size_t)((rr & 63) * 64 + (rr >> 6));   // (S,B)->(B,S)
        __builtin_nontemporal_store(acc[mf][nf][j] + bv, &C[orow * (size_t)V_ + cc]);
      }
    }
  }
}

// ---------------- fused persistent 2-layer bidirectional LSTM (R15/R17-proven) ----------------
#define LDW0 520    // l0: 64 rows x (512+8)
#define LDW1 1544   // l1: 32 rows x (1536+8)
#define NBLK 192

__global__ __launch_bounds__(256) void k_fused_lstm(
    const unsigned short* __restrict__ h0i,   // (2,B,H) bf16
    const unsigned short* __restrict__ h1i,   // (2,B,H) bf16
    const float* __restrict__ cell,           // (4,B,H) fp32 [l0f,l0b,l1f,l1b]
    const unsigned short* __restrict__ whh0,  // (2,2048,512) bf16
    const unsigned short* __restrict__ wih1,  // (2,2048,1024) bf16
    const unsigned short* __restrict__ whh1,  // (2,2048,512) bf16
    const float* __restrict__ b1s,            // (2,2048) fp32
    const unsigned short* __restrict__ G0u,   // d_out as ushort (bf16 G0 tails)
    unsigned short* __restrict__ H0,          // (SB,1024) bf16
    unsigned short* __restrict__ O1,          // (SB,1024) bf16
    unsigned* __restrict__ cnt0, unsigned* __restrict__ cnt1) {
  __shared__ unsigned short SM[32 * LDW1];    // 98,816 B
  __shared__ __align__(16) unsigned short HS[64 * 16];
  int tid = threadIdx.x;
  int w = tid >> 6, l = tid & 63;
  int lr = l & 15, hi = l >> 4;

  if (blockIdx.x < 64) {
    // ================= LAYER 0 =================
    int d = blockIdx.x >> 5, jt = blockIdx.x & 31;
    const unsigned short* Wd = whh0 + (size_t)d * (G4 * H_);
    for (int c = tid; c < 64 * 64; c += 256) {
      int row = c >> 6, ck = c & 63;
      int g = row >> 4, r16 = row & 15;
      *(int4*)&SM[row * LDW0 + ck * 8] =
          *(const int4*)&Wd[(size_t)(g * H_ + jt * 16 + r16) * H_ + ck * 8];
    }
    int j = jt * 16 + lr;
    int b0 = w * 16 + hi * 4;
    f32x4 creg;
    {
      const float* cd = cell + (size_t)d * (B_ * H_);
#pragma unroll
      for (int jj = 0; jj < 4; jj++) creg[jj] = cd[(size_t)(b0 + jj) * H_ + j];
    }
    __syncthreads();
    float gv[4][4];
    auto preloadG = [&](int t) {
#pragma unroll
      for (int jj = 0; jj < 4; jj++) {
        const unsigned short* Gb =
            G0u + (size_t)(t * B_ + b0 + jj) * OROW_US + GTAIL_US + d * 2048 + j;
#pragma unroll
        for (int g = 0; g < 4; g++) gv[g][jj] = bf2f(Gb[g * 512]);
      }
    };
    preloadG(0);
    for (int t = 0; t < S_; ++t) {
      if (t >= 1) {
        if (tid < 4) spin_ge(&cnt0[CIDX(t - 1, d, tid)], 8);
        __syncthreads();
      }
      const unsigned short* hp = (t == 0) ? h0i + (size_t)d * (B_ * H_)
                                          : H0 + (size_t)(t - 1) * B_ * 1024 + d * 512;
      size_t hstr = (t == 0) ? (size_t)H_ : 1024;
      const unsigned short* arow = hp + (size_t)(w * 16 + lr) * hstr + hi * 8;
      f32x4 acc[4] = {};
#pragma unroll
      for (int ki = 0; ki < 16; ki++) {
        short8 a = *(const short8*)&arow[ki * 32];
#pragma unroll
        for (int g = 0; g < 4; g++) {
          short8 bfr = *(const short8*)&SM[(g * 16 + lr) * LDW0 + ki * 32 + hi * 8];
          acc[g] = __builtin_amdgcn_mfma_f32_16x16x32_bf16(a, bfr, acc[g], 0, 0, 0);
        }
      }
#pragma unroll
      for (int jj = 0; jj < 4; jj++) {
        float gi = acc[0][jj] + gv[0][jj];
        float gf = acc[1][jj] + gv[1][jj];
        float gg = acc[2][jj] + gv[2][jj];
        float go = acc[3][jj] + gv[3][jj];
        float c = sigm(gf) * creg[jj] + sigm(gi) * tanh_fast(gg);
        creg[jj] = c;
        HS[(b0 + jj) * 16 + lr] = f2bf(sigm(go) * tanh_fast(c));
      }
      __syncthreads();
      unsigned short* Ho = H0 + (size_t)t * B_ * 1024 + d * 512 + jt * 16;
      if (tid < 128) {
        int r = tid >> 1, half = tid & 1;
        st128_sys(&Ho[(size_t)r * 1024 + half * 8], *(const i32x4*)&HS[r * 16 + half * 8]);
      }
      wait_vm0();
      __syncthreads();
      if (tid == 0) arrive(&cnt0[CIDX(t, d, jt & 3)]);
      if (t + 1 < S_) preloadG(t + 1);
    }
  } else {
    // ================= LAYER 1 (pipelined) =================
    int idx = blockIdx.x - 64;
    int d = idx >> 6, jt8 = idx & 63;
    int j0 = jt8 * 8;
    {
      const unsigned short* Wih = wih1 + (size_t)d * (G4 * 1024);
      const unsigned short* Whh = whh1 + (size_t)d * (G4 * H_);
      for (int c = tid; c < 32 * 192; c += 256) {
        int r = c / 192, ck = c - r * 192;
        int g = r >> 3, jc = r & 7;
        const unsigned short* src =
            (ck < 128) ? Wih + (size_t)(g * H_ + j0 + jc) * 1024 + ck * 8
                       : Whh + (size_t)(g * H_ + j0 + jc) * H_ + (ck - 128) * 8;
        *(int4*)&SM[r * LDW1 + ck * 8] = *(const int4*)src;
      }
    }
    int j = j0 + (lr & 7);
    const float* b1d = b1s + d * G4;
    float bi_ = b1d[j], bf_ = b1d[512 + j], bg_ = b1d[1024 + j], bo_ = b1d[1536 + j];
    int b0 = w * 16 + hi * 4;
    f32x4 creg = {};
    if (lr < 8) {
      const float* cd = cell + (size_t)(2 + d) * (B_ * H_);
#pragma unroll
      for (int jj = 0; jj < 4; jj++) creg[jj] = cd[(size_t)(b0 + jj) * H_ + j];
    }
    __syncthreads();

    f32x4 acc0, acc1;
    {
      if (tid < 8) spin_ge(&cnt0[CIDX(0, 0, 0) + tid * 64], 8);
      __syncthreads();
      acc0 = (f32x4){}; acc1 = (f32x4){};
      const unsigned short* x1row = H0 + ((size_t)0 * B_ + w * 16 + lr) * 1024 + hi * 8;
#pragma unroll 8
      for (int ki = 0; ki < 32; ki++) {
        short8 a = *(const short8*)&x1row[ki * 32];
        short8 bA = *(const short8*)&SM[(size_t)lr * LDW1 + ki * 32 + hi * 8];
        short8 bB = *(const short8*)&SM[(size_t)(16 + lr) * LDW1 + ki * 32 + hi * 8];
        acc0 = __builtin_amdgcn_mfma_f32_16x16x32_bf16(a, bA, acc0, 0, 0, 0);
        acc1 = __builtin_amdgcn_mfma_f32_16x16x32_bf16(a, bB, acc1, 0, 0, 0);
      }
    }
    for (int t = 0; t < S_; ++t) {
      if (t >= 1) {
        if (tid < 4) spin_ge(&cnt1[CIDX(t - 1, d, tid)], 16);
        __syncthreads();
      }
      const unsigned short* hprev = (t == 0)
          ? h1i + (size_t)d * (B_ * H_) + (size_t)(w * 16 + lr) * H_ + hi * 8
          : O1 + ((size_t)(t - 1) * B_ + w * 16 + lr) * 1024 + d * 512 + hi * 8;
#pragma unroll 8
      for (int ki = 0; ki < 16; ki++) {
        short8 a = *(const short8*)&hprev[ki * 32];
        short8 bA = *(const short8*)&SM[(size_t)lr * LDW1 + 1024 + ki * 32 + hi * 8];
        short8 bB = *(const short8*)&SM[(size_t)(16 + lr) * LDW1 + 1024 + ki * 32 + hi * 8];
        acc0 = __builtin_amdgcn_mfma_f32_16x16x32_bf16(a, bA, acc0, 0, 0, 0);
        acc1 = __builtin_amdgcn_mfma_f32_16x16x32_bf16(a, bB, acc1, 0, 0, 0);
      }
      float pf[4], po[4];
#pragma unroll
      for (int jj = 0; jj < 4; jj++) {
        pf[jj] = __shfl_xor(acc0[jj], 8);
        po[jj] = __shfl_xor(acc1[jj], 8);
      }
      if (lr < 8) {
#pragma unroll
        for (int jj = 0; jj < 4; jj++) {
          float gi = acc0[jj] + bi_;
          float gf = pf[jj] + bf_;
          float gg = acc1[jj] + bg_;
          float go = po[jj] + bo_;
          float c = sigm(gf) * creg[jj] + sigm(gi) * tanh_fast(gg);
          creg[jj] = c;
          HS[(b0 + jj) * 8 + lr] = f2bf(sigm(go) * tanh_fast(c));
        }
      }
      __syncthreads();
      unsigned short* Oo = O1 + (size_t)t * B_ * 1024 + d * 512 + j0;
      if (tid < 64) st128_sys(&Oo[(size_t)tid * 1024], *(const i32x4*)&HS[tid * 8]);
      wait_vm0();
      __syncthreads();
      if (tid == 0 && t + 1 < S_) arrive(&cnt1[CIDX(t, d, jt8 & 3)]);
      if (t + 1 < S_) {
        if (tid < 8) spin_ge(&cnt0[CIDX(t + 1, 0, 0) + tid * 64], 8);
        __syncthreads();
        acc0 = (f32x4){}; acc1 = (f32x4){};
        const unsigned short* x1row =
            H0 + ((size_t)(t + 1) * B_ + w * 16 + lr) * 1024 + hi * 8;
#pragma unroll 8
        for (int ki = 0; ki < 32; ki++) {
          short8 a = *(const short8*)&x1row[ki * 32];
          short8 bA = *(const short8*)&SM[(size_t)lr * LDW1 + ki * 32 + hi * 8];
          short8 bB = *(const short8*)&SM[(size_t)(16 + lr) * LDW1 + ki * 32 + hi * 8];
          acc0 = __builtin_amdgcn_mfma_f32_16x16x32_bf16(a, bA, acc0, 0, 0, 0);
          acc1 = __builtin_amdgcn_mfma_f32_16x16x32_bf16(a, bB, acc1, 0, 0, 0);
        }
      }
    }
  }
}

extern "C" void kernel_launch(void* const* d_in, const int* in_sizes, int n_in,
                              void* d_out, int out_size, void* d_ws, size_t ws_size,
                              hipStream_t stream) {
  const float* hidden = (const float*)d_in[0];
  const float* cell   = (const float*)d_in[1];
  const int*   Y      = (const int*)d_in[2];
  const float* emb    = (const float*)d_in[3];
  const float* wih0   = (const float*)d_in[4];
  const float* whh0   = (const float*)d_in[5];
  const float* bih0   = (const float*)d_in[6];
  const float* bhh0   = (const float*)d_in[7];
  const float* wih1   = (const float*)d_in[8];
  const float* whh1   = (const float*)d_in[9];
  const float* bih1   = (const float*)d_in[10];
  const float* bhh1   = (const float*)d_in[11];
  const float* fcw    = (const float*)d_in[12];
  const float* fcb    = (const float*)d_in[13];

  char* ws = (char*)d_ws;
  size_t off = 0;
  auto alloc = [&](size_t bytes) {
    void* p = ws + off;
    off += (bytes + 255) & ~(size_t)255;
    return p;
  };
  unsigned short* wih0b = (unsigned short*)alloc((size_t)2 * G4 * E_ * 2);
  unsigned short* whh0b = (unsigned short*)alloc((size_t)2 * G4 * H_ * 2);
  unsigned short* wih1b = (unsigned short*)alloc((size_t)2 * G4 * 1024 * 2);
  unsigned short* whh1b = (unsigned short*)alloc((size_t)2 * G4 * H_ * 2);
  unsigned short* fcwb  = (unsigned short*)alloc((size_t)V_ * 1024 * 2);
  unsigned short* Xb    = (unsigned short*)alloc((size_t)SB * E_ * 2);
  unsigned short* H0    = (unsigned short*)alloc((size_t)SB * 1024 * 2);
  unsigned short* O1    = (unsigned short*)alloc((size_t)SB * 1024 * 2);
  unsigned short* h0i   = (unsigned short*)alloc((size_t)2 * B_ * H_ * 2);
  unsigned short* h1i   = (unsigned short*)alloc((size_t)2 * B_ * H_ * 2);
  float* b0s = (float*)alloc((size_t)2 * G4 * 4);
  float* b1s = (float*)alloc((size_t)2 * G4 * 4);
  unsigned* cnt0 = (unsigned*)alloc(CNT_BYTES);
  unsigned* cnt1 = (unsigned*)alloc(CNT_BYTES);
  (void)ws_size;

  // --- prep ---
  k_f2bf4<<<2048, 256, 0, stream>>>(wih0, whh0, wih1, whh1, wih0b);
  k_f2bf<<<4096, 256, 0, stream>>>(fcw, fcwb, V_ * 1024);
  k_addbias<<<16, 256, 0, stream>>>(bih0, bhh0, b0s, 2 * G4);
  k_addbias<<<16, 256, 0, stream>>>(bih1, bhh1, b1s, 2 * G4);
  k_gather<<<SB, 256, 0, stream>>>(Y, emb, Xb);
  k_init_h<<<512, 256, 0, stream>>>(hidden, h0i, h1i);
  (void)hipMemsetAsync(cnt0, 0, CNT_BYTES, stream);
  (void)hipMemsetAsync(cnt1, 0, CNT_BYTES, stream);

  // --- layer-0 input gates -> bf16 G0 in d_out row tails ---
  k_gemm_g0<<<1024, 256, 0, stream>>>(Xb, wih0b, b0s, (unsigned short*)d_out,
                                      E_, SB / 128, 1024);

  // --- fused persistent recurrence (self-timed chains, R15 structure) ---
  k_fused_lstm<<<NBLK, 256, 0, stream>>>(h0i, h1i, cell, whh0b, wih1b, whh1b,
                                         b1s, (const unsigned short*)d_out,
                                         H0, O1, cnt0, cnt1);

  // --- final projection: 256^2 counted-vmcnt pipelined GEMM ---
  k_gemm_fc256<<<2000, 512, 0, stream>>>(O1, fcwb, fcb, (float*)d_out);
}

// Round 19
// 1083.075 us; speedup vs baseline: 2.8973x; 1.0190x over previous
//
#include <hip/hip_runtime.h>
#include <hip/hip_bf16.h>
#include <stdint.h>

#define S_ 64
#define B_ 64
#define E_ 512
#define H_ 512
#define V_ 32000
#define G4 2048   // 4*H
#define SB 4096   // S*B

// d_out row = 32000 fp32 = 64000 ushort; G0 (bf16) lives in the tail 4096
// ushorts of each row. Sequential: final GEMM overwrites tails after rec.
#define OROW_US 64000
#define GTAIL_US 59904   // 29952 fp32 * 2

typedef __attribute__((ext_vector_type(8))) short short8;
typedef __attribute__((ext_vector_type(4))) float f32x4;
typedef __attribute__((ext_vector_type(4))) int i32x4;

static __device__ __forceinline__ unsigned short f2bf(float f) {
  unsigned u = __float_as_uint(f);
  u += 0x7fff + ((u >> 16) & 1);   // RNE
  return (unsigned short)(u >> 16);
}
static __device__ __forceinline__ unsigned pk2(float a, float b) {
  return (unsigned)f2bf(a) | ((unsigned)f2bf(b) << 16);
}
static __device__ __forceinline__ float bf2f(unsigned short u) {
  return __uint_as_float((unsigned)u << 16);
}
// fast gate activations via native v_exp_f32 (exp2)
static __device__ __forceinline__ float sigm(float x) {
  return 1.f / (1.f + exp2f(x * -1.44269504f));
}
static __device__ __forceinline__ float tanh_fast(float x) {
  float e = exp2f(x * 2.88539008f);   // e^(2x)
  return 1.f - 2.f / (e + 1.f);
}

__device__ __forceinline__ void gload_lds16(const void* g, void* l) {
  __builtin_amdgcn_global_load_lds(
      (const __attribute__((address_space(1))) void*)g,
      (__attribute__((address_space(3))) void*)l, 16, 0, 0);
}

// coherent (device-visible) 16-byte store: write-through past the XCD L2
__device__ __forceinline__ void st128_sys(void* p, i32x4 v) {
  asm volatile("global_store_dwordx4 %0, %1, off sc0 sc1"
               :: "v"((unsigned long long)p), "v"(v) : "memory");
}
__device__ __forceinline__ void wait_vm0() {
  asm volatile("s_waitcnt vmcnt(0)" ::: "memory");
}

__device__ __forceinline__ void spin_ge(unsigned* c, unsigned tgt) {
  while (__hip_atomic_load(c, __ATOMIC_RELAXED, __HIP_MEMORY_SCOPE_AGENT) < tgt)
    __builtin_amdgcn_s_sleep(1);
}
__device__ __forceinline__ void arrive(unsigned* c) {
  __hip_atomic_fetch_add(c, 1u, __ATOMIC_RELAXED, __HIP_MEMORY_SCOPE_AGENT);
}

#define CIDX(t, d, p) ((((t) * 8) + ((d) * 4) + (p)) * 64)
#define CNT_BYTES (64 * 8 * 64 * 4)

__global__ void k_f2bf4(const float* __restrict__ s0, const float* __restrict__ s1,
                        const float* __restrict__ s2, const float* __restrict__ s3,
                        unsigned short* __restrict__ dst) {
  const int c0 = 2 * G4 * E_ / 8, c1 = c0 + 2 * G4 * H_ / 8,
            c2 = c1 + 2 * G4 * 1024 / 8, c3 = c2 + 2 * G4 * H_ / 8;
  int i8 = blockIdx.x * blockDim.x + threadIdx.x;
  int stride = gridDim.x * blockDim.x;
  for (; i8 < c3; i8 += stride) {
    const float* s; int o8;
    if (i8 < c0) { s = s0; o8 = i8; }
    else if (i8 < c1) { s = s1; o8 = i8 - c0; }
    else if (i8 < c2) { s = s2; o8 = i8 - c1; }
    else { s = s3; o8 = i8 - c2; }
    int o = o8 * 8;
    float4 x = *(const float4*)&s[o];
    float4 y = *(const float4*)&s[o + 4];
    i32x4 v = {(int)pk2(x.x, x.y), (int)pk2(x.z, x.w),
               (int)pk2(y.x, y.y), (int)pk2(y.z, y.w)};
    *(i32x4*)&dst[i8 * 8] = v;
  }
}

__global__ void k_f2bf(const float* __restrict__ in, unsigned short* __restrict__ out, int n) {
  int i = blockIdx.x * blockDim.x + threadIdx.x;
  int stride = gridDim.x * blockDim.x;
  for (; i < n; i += stride) out[i] = f2bf(in[i]);
}

__global__ void k_addbias(const float* __restrict__ a, const float* __restrict__ b,
                          float* __restrict__ out, int n) {
  int i = blockIdx.x * blockDim.x + threadIdx.x;
  if (i < n) out[i] = a[i] + b[i];
}

__global__ void k_gather(const int* __restrict__ Y, const float* __restrict__ emb,
                         unsigned short* __restrict__ X) {
  int sb = blockIdx.x;
  int t = sb >> 6, b = sb & 63;
  int idx = (t == 0) ? Y[b * S_ + 1] : Y[b * S_ + t - 1];
  const float* src = emb + (size_t)idx * E_;
  unsigned short* dst = X + (size_t)sb * E_;
  for (int e = threadIdx.x; e < E_; e += blockDim.x) dst[e] = f2bf(src[e]);
}

__global__ void k_init_h(const float* __restrict__ hid,
                         unsigned short* __restrict__ h0i, unsigned short* __restrict__ h1i) {
  int i = blockIdx.x * blockDim.x + threadIdx.x;
  if (i >= 4 * B_ * H_) return;
  unsigned short v = f2bf(hid[i]);
  if (i < 2 * B_ * H_) h0i[i] = v;
  else h1i[i - 2 * B_ * H_] = v;
}

// ---------------- G0 GEMM: bf16 into d_out row tails (R10-proven) ----------------
__global__ __launch_bounds__(256) void k_gemm_g0(
    const unsigned short* __restrict__ A, const unsigned short* __restrict__ B,
    const float* __restrict__ bias, unsigned short* __restrict__ C,
    int K, int nTM, int nwg) {
  __shared__ unsigned short Als[128 * 32];
  __shared__ unsigned short Bls[128 * 32];
  int tid = threadIdx.x;
  int o = blockIdx.x;
  int wg = (o & 7) * (nwg >> 3) + (o >> 3);
  int bm = wg % nTM, bn = wg / nTM;
  int w = tid >> 6, l = tid & 63;
  int wr = w >> 1, wc = w & 1;
  int lr = l & 15, hi = l >> 4;
  int c0 = w * 128 + l;
  int row0 = c0 >> 2, ks0 = (((c0 & 3) ^ (row0 & 3)) * 8);
  int c1 = c0 + 64;
  int row1 = c1 >> 2, ks1 = (((c1 & 3) ^ (row1 & 3)) * 8);
  const unsigned short* Ab = A + (size_t)(bm * 128) * K;
  const unsigned short* Bb = B + (size_t)(bn * 128) * K;
  unsigned short* AlsW = &Als[w * 1024];
  unsigned short* BlsW = &Bls[w * 1024];
  int co = ((hi ^ (lr & 3)) * 8);
  f32x4 acc[4][4] = {};
  for (int kk = 0; kk < K; kk += 32) {
    __syncthreads();
    gload_lds16(Ab + (size_t)row0 * K + kk + ks0, AlsW);
    gload_lds16(Ab + (size_t)row1 * K + kk + ks1, AlsW + 512);
    gload_lds16(Bb + (size_t)row0 * K + kk + ks0, BlsW);
    gload_lds16(Bb + (size_t)row1 * K + kk + ks1, BlsW + 512);
    __syncthreads();
    short8 af[4], bfr[4];
#pragma unroll
    for (int r = 0; r < 4; r++)
      af[r] = *(const short8*)&Als[(wr * 64 + r * 16 + lr) * 32 + co];
#pragma unroll
    for (int c4 = 0; c4 < 4; c4++)
      bfr[c4] = *(const short8*)&Bls[(wc * 64 + c4 * 16 + lr) * 32 + co];
#pragma unroll
    for (int r = 0; r < 4; r++)
#pragma unroll
      for (int c4 = 0; c4 < 4; c4++)
        acc[r][c4] = __builtin_amdgcn_mfma_f32_16x16x32_bf16(af[r], bfr[c4], acc[r][c4], 0, 0, 0);
  }
  int rbase = bm * 128 + wr * 64 + hi * 4;
  int cbase = bn * 128 + wc * 64 + lr;
#pragma unroll
  for (int r = 0; r < 4; r++) {
#pragma unroll
    for (int c4 = 0; c4 < 4; c4++) {
      int cc = cbase + c4 * 16;
      float bv = bias[cc];
#pragma unroll
      for (int j = 0; j < 4; j++) {
        int rr = rbase + r * 16 + j;
        C[(size_t)rr * OROW_US + GTAIL_US + cc] = f2bf(acc[r][c4][j] + bv);
      }
    }
  }
}

// ------- final GEMM: 256x256 tile, BK=64, counted-vmcnt pipeline (R18-proven) -------
// R19 delta: bn-major-within-XCD block order — XCD c covers bm in {2c,2c+1} x all
// bn, so the per-XCD A working set (2 x 512KB) stays L2-resident (A re-read
// traffic 1GB -> ~16MB); B streams once per XCD from L3.
__global__ __launch_bounds__(512, 1) void k_gemm_fc256(
    const unsigned short* __restrict__ A,   // O1 (4096,1024) bf16
    const unsigned short* __restrict__ B,   // fcwb (32000,1024) bf16
    const float* __restrict__ bias, float* __restrict__ C) {
  __shared__ unsigned short LB[65536];      // 131072 B
  int tid = threadIdx.x;
  int w = tid >> 6, l = tid & 63;
  int lr = l & 15, hi = l >> 4;
  int wm = w >> 2, wn = w & 3;
  int o = blockIdx.x;
  int wg = (o & 7) * 250 + (o >> 3);        // bijective XCD swizzle (2000%8==0)
  int bn = wg % 125, bm = wg / 125;         // bn-major within XCD (A L2-resident)
  const unsigned short* Ab = A + (size_t)(bm * 256) * 1024;
  const unsigned short* Bb = B + (size_t)(bn * 256) * 1024;
  int srcoff[4], cb[4];
#pragma unroll
  for (int r = 0; r < 4; r++) {
    int c = r * 512 + tid;
    int row = c >> 3, stc = c & 7;
    srcoff[r] = row * 1024 + (stc ^ (row & 7)) * 8;
    cb[r] = (r * 512 + w * 64) * 8;         // wave-uniform LDS elem base
  }
  auto stage = [&](int kt) {
    int slot = (kt & 1) * 32768;
#pragma unroll
    for (int r = 0; r < 4; r++)
      gload_lds16(Ab + srcoff[r] + kt * 64, &LB[slot + cb[r]]);
#pragma unroll
    for (int r = 0; r < 4; r++)
      gload_lds16(Bb + srcoff[r] + kt * 64, &LB[slot + 16384 + cb[r]]);
  };
  f32x4 acc[8][4] = {};
  stage(0);
  stage(1);
  for (int t = 0; t < 16; ++t) {
    if (t < 15) asm volatile("s_waitcnt vmcnt(8)" ::: "memory");
    else        asm volatile("s_waitcnt vmcnt(0)" ::: "memory");
    __builtin_amdgcn_s_barrier();
    __builtin_amdgcn_sched_barrier(0);
    const unsigned short* bufA = &LB[(t & 1) * 32768];
    const unsigned short* bufB = bufA + 16384;
    __builtin_amdgcn_s_setprio(1);
#pragma unroll
    for (int kh = 0; kh < 2; kh++) {
      short8 af[8], bf[4];
      int ch = ((kh * 4 + hi) ^ (lr & 7)) * 8;
#pragma unroll
      for (int mf = 0; mf < 8; mf++)
        af[mf] = *(const short8*)&bufA[(wm * 128 + mf * 16 + lr) * 64 + ch];
#pragma unroll
      for (int nf = 0; nf < 4; nf++)
        bf[nf] = *(const short8*)&bufB[(wn * 64 + nf * 16 + lr) * 64 + ch];
#pragma unroll
      for (int mf = 0; mf < 8; mf++)
#pragma unroll
        for (int nf = 0; nf < 4; nf++)
          acc[mf][nf] = __builtin_amdgcn_mfma_f32_16x16x32_bf16(af[mf], bf[nf], acc[mf][nf], 0, 0, 0);
    }
    __builtin_amdgcn_s_setprio(0);
    __builtin_amdgcn_sched_barrier(0);
    __builtin_amdgcn_s_barrier();
    if (t + 2 < 16) stage(t + 2);
  }
#pragma unroll
  for (int mf = 0; mf < 8; mf++) {
#pragma unroll
    for (int nf = 0; nf < 4; nf++) {
      int cc = bn * 256 + wn * 64 + nf * 16 + lr;
      float bv = bias[cc];
#pragma unroll
      for (int j = 0; j < 4; j++) {
        int rr = bm * 256 + wm * 128 + mf * 16 + hi * 4 + j;
        size_t orow = (size_t)((rr & 63) * 64 + (rr >> 6));   // (S,B)->(B,S)
        __builtin_nontemporal_store(acc[mf][nf][j] + bv, &C[orow * (size_t)V_ + cc]);
      }
    }
  }
}

// ---------------- fused persistent 2-layer bidirectional LSTM (R15/R17-proven) ----------------
#define LDW0 520    // l0: 64 rows x (512+8)
#define LDW1 1544   // l1: 32 rows x (1536+8)
#define NBLK 192

__global__ __launch_bounds__(256) void k_fused_lstm(
    const unsigned short* __restrict__ h0i,   // (2,B,H) bf16
    const unsigned short* __restrict__ h1i,   // (2,B,H) bf16
    const float* __restrict__ cell,           // (4,B,H) fp32 [l0f,l0b,l1f,l1b]
    const unsigned short* __restrict__ whh0,  // (2,2048,512) bf16
    const unsigned short* __restrict__ wih1,  // (2,2048,1024) bf16
    const unsigned short* __restrict__ whh1,  // (2,2048,512) bf16
    const float* __restrict__ b1s,            // (2,2048) fp32
    const unsigned short* __restrict__ G0u,   // d_out as ushort (bf16 G0 tails)
    unsigned short* __restrict__ H0,          // (SB,1024) bf16
    unsigned short* __restrict__ O1,          // (SB,1024) bf16
    unsigned* __restrict__ cnt0, unsigned* __restrict__ cnt1) {
  __shared__ unsigned short SM[32 * LDW1];    // 98,816 B
  __shared__ __align__(16) unsigned short HS[64 * 16];
  int tid = threadIdx.x;
  int w = tid >> 6, l = tid & 63;
  int lr = l & 15, hi = l >> 4;

  if (blockIdx.x < 64) {
    // ================= LAYER 0 =================
    int d = blockIdx.x >> 5, jt = blockIdx.x & 31;
    const unsigned short* Wd = whh0 + (size_t)d * (G4 * H_);
    for (int c = tid; c < 64 * 64; c += 256) {
      int row = c >> 6, ck = c & 63;
      int g = row >> 4, r16 = row & 15;
      *(int4*)&SM[row * LDW0 + ck * 8] =
          *(const int4*)&Wd[(size_t)(g * H_ + jt * 16 + r16) * H_ + ck * 8];
    }
    int j = jt * 16 + lr;
    int b0 = w * 16 + hi * 4;
    f32x4 creg;
    {
      const float* cd = cell + (size_t)d * (B_ * H_);
#pragma unroll
      for (int jj = 0; jj < 4; jj++) creg[jj] = cd[(size_t)(b0 + jj) * H_ + j];
    }
    __syncthreads();
    float gv[4][4];
    auto preloadG = [&](int t) {
#pragma unroll
      for (int jj = 0; jj < 4; jj++) {
        const unsigned short* Gb =
            G0u + (size_t)(t * B_ + b0 + jj) * OROW_US + GTAIL_US + d * 2048 + j;
#pragma unroll
        for (int g = 0; g < 4; g++) gv[g][jj] = bf2f(Gb[g * 512]);
      }
    };
    preloadG(0);
    for (int t = 0; t < S_; ++t) {
      if (t >= 1) {
        if (tid < 4) spin_ge(&cnt0[CIDX(t - 1, d, tid)], 8);
        __syncthreads();
      }
      const unsigned short* hp = (t == 0) ? h0i + (size_t)d * (B_ * H_)
                                          : H0 + (size_t)(t - 1) * B_ * 1024 + d * 512;
      size_t hstr = (t == 0) ? (size_t)H_ : 1024;
      const unsigned short* arow = hp + (size_t)(w * 16 + lr) * hstr + hi * 8;
      f32x4 acc[4] = {};
#pragma unroll
      for (int ki = 0; ki < 16; ki++) {
        short8 a = *(const short8*)&arow[ki * 32];
#pragma unroll
        for (int g = 0; g < 4; g++) {
          short8 bfr = *(const short8*)&SM[(g * 16 + lr) * LDW0 + ki * 32 + hi * 8];
          acc[g] = __builtin_amdgcn_mfma_f32_16x16x32_bf16(a, bfr, acc[g], 0, 0, 0);
        }
      }
#pragma unroll
      for (int jj = 0; jj < 4; jj++) {
        float gi = acc[0][jj] + gv[0][jj];
        float gf = acc[1][jj] + gv[1][jj];
        float gg = acc[2][jj] + gv[2][jj];
        float go = acc[3][jj] + gv[3][jj];
        float c = sigm(gf) * creg[jj] + sigm(gi) * tanh_fast(gg);
        creg[jj] = c;
        HS[(b0 + jj) * 16 + lr] = f2bf(sigm(go) * tanh_fast(c));
      }
      __syncthreads();
      unsigned short* Ho = H0 + (size_t)t * B_ * 1024 + d * 512 + jt * 16;
      if (tid < 128) {
        int r = tid >> 1, half = tid & 1;
        st128_sys(&Ho[(size_t)r * 1024 + half * 8], *(const i32x4*)&HS[r * 16 + half * 8]);
      }
      wait_vm0();
      __syncthreads();
      if (tid == 0) arrive(&cnt0[CIDX(t, d, jt & 3)]);
      if (t + 1 < S_) preloadG(t + 1);
    }
  } else {
    // ================= LAYER 1 (pipelined) =================
    int idx = blockIdx.x - 64;
    int d = idx >> 6, jt8 = idx & 63;
    int j0 = jt8 * 8;
    {
      const unsigned short* Wih = wih1 + (size_t)d * (G4 * 1024);
      const unsigned short* Whh = whh1 + (size_t)d * (G4 * H_);
      for (int c = tid; c < 32 * 192; c += 256) {
        int r = c / 192, ck = c - r * 192;
        int g = r >> 3, jc = r & 7;
        const unsigned short* src =
            (ck < 128) ? Wih + (size_t)(g * H_ + j0 + jc) * 1024 + ck * 8
                       : Whh + (size_t)(g * H_ + j0 + jc) * H_ + (ck - 128) * 8;
        *(int4*)&SM[r * LDW1 + ck * 8] = *(const int4*)src;
      }
    }
    int j = j0 + (lr & 7);
    const float* b1d = b1s + d * G4;
    float bi_ = b1d[j], bf_ = b1d[512 + j], bg_ = b1d[1024 + j], bo_ = b1d[1536 + j];
    int b0 = w * 16 + hi * 4;
    f32x4 creg = {};
    if (lr < 8) {
      const float* cd = cell + (size_t)(2 + d) * (B_ * H_);
#pragma unroll
      for (int jj = 0; jj < 4; jj++) creg[jj] = cd[(size_t)(b0 + jj) * H_ + j];
    }
    __syncthreads();

    f32x4 acc0, acc1;
    {
      if (tid < 8) spin_ge(&cnt0[CIDX(0, 0, 0) + tid * 64], 8);
      __syncthreads();
      acc0 = (f32x4){}; acc1 = (f32x4){};
      const unsigned short* x1row = H0 + ((size_t)0 * B_ + w * 16 + lr) * 1024 + hi * 8;
#pragma unroll 8
      for (int ki = 0; ki < 32; ki++) {
        short8 a = *(const short8*)&x1row[ki * 32];
        short8 bA = *(const short8*)&SM[(size_t)lr * LDW1 + ki * 32 + hi * 8];
        short8 bB = *(const short8*)&SM[(size_t)(16 + lr) * LDW1 + ki * 32 + hi * 8];
        acc0 = __builtin_amdgcn_mfma_f32_16x16x32_bf16(a, bA, acc0, 0, 0, 0);
        acc1 = __builtin_amdgcn_mfma_f32_16x16x32_bf16(a, bB, acc1, 0, 0, 0);
      }
    }
    for (int t = 0; t < S_; ++t) {
      if (t >= 1) {
        if (tid < 4) spin_ge(&cnt1[CIDX(t - 1, d, tid)], 16);
        __syncthreads();
      }
      const unsigned short* hprev = (t == 0)
          ? h1i + (size_t)d * (B_ * H_) + (size_t)(w * 16 + lr) * H_ + hi * 8
          : O1 + ((size_t)(t - 1) * B_ + w * 16 + lr) * 1024 + d * 512 + hi * 8;
#pragma unroll 8
      for (int ki = 0; ki < 16; ki++) {
        short8 a = *(const short8*)&hprev[ki * 32];
        short8 bA = *(const short8*)&SM[(size_t)lr * LDW1 + 1024 + ki * 32 + hi * 8];
        short8 bB = *(const short8*)&SM[(size_t)(16 + lr) * LDW1 + 1024 + ki * 32 + hi * 8];
        acc0 = __builtin_amdgcn_mfma_f32_16x16x32_bf16(a, bA, acc0, 0, 0, 0);
        acc1 = __builtin_amdgcn_mfma_f32_16x16x32_bf16(a, bB, acc1, 0, 0, 0);
      }
      float pf[4], po[4];
#pragma unroll
      for (int jj = 0; jj < 4; jj++) {
        pf[jj] = __shfl_xor(acc0[jj], 8);
        po[jj] = __shfl_xor(acc1[jj], 8);
      }
      if (lr < 8) {
#pragma unroll
        for (int jj = 0; jj < 4; jj++) {
          float gi = acc0[jj] + bi_;
          float gf = pf[jj] + bf_;
          float gg = acc1[jj] + bg_;
          float go = po[jj] + bo_;
          float c = sigm(gf) * creg[jj] + sigm(gi) * tanh_fast(gg);
          creg[jj] = c;
          HS[(b0 + jj) * 8 + lr] = f2bf(sigm(go) * tanh_fast(c));
        }
      }
      __syncthreads();
      unsigned short* Oo = O1 + (size_t)t * B_ * 1024 + d * 512 + j0;
      if (tid < 64) st128_sys(&Oo[(size_t)tid * 1024], *(const i32x4*)&HS[tid * 8]);
      wait_vm0();
      __syncthreads();
      if (tid == 0 && t + 1 < S_) arrive(&cnt1[CIDX(t, d, jt8 & 3)]);
      if (t + 1 < S_) {
        if (tid < 8) spin_ge(&cnt0[CIDX(t + 1, 0, 0) + tid * 64], 8);
        __syncthreads();
        acc0 = (f32x4){}; acc1 = (f32x4){};
        const unsigned short* x1row =
            H0 + ((size_t)(t + 1) * B_ + w * 16 + lr) * 1024 + hi * 8;
#pragma unroll 8
        for (int ki = 0; ki < 32; ki++) {
          short8 a = *(const short8*)&x1row[ki * 32];
          short8 bA = *(const short8*)&SM[(size_t)lr * LDW1 + ki * 32 + hi * 8];
          short8 bB = *(const short8*)&SM[(size_t)(16 + lr) * LDW1 + ki * 32 + hi * 8];
          acc0 = __builtin_amdgcn_mfma_f32_16x16x32_bf16(a, bA, acc0, 0, 0, 0);
          acc1 = __builtin_amdgcn_mfma_f32_16x16x32_bf16(a, bB, acc1, 0, 0, 0);
        }
      }
    }
  }
}

extern "C" void kernel_launch(void* const* d_in, const int* in_sizes, int n_in,
                              void* d_out, int out_size, void* d_ws, size_t ws_size,
                              hipStream_t stream) {
  const float* hidden = (const float*)d_in[0];
  const float* cell   = (const float*)d_in[1];
  const int*   Y      = (const int*)d_in[2];
  const float* emb    = (const float*)d_in[3];
  const float* wih0   = (const float*)d_in[4];
  const float* whh0   = (const float*)d_in[5];
  const float* bih0   = (const float*)d_in[6];
  const float* bhh0   = (const float*)d_in[7];
  const float* wih1   = (const float*)d_in[8];
  const float* whh1   = (const float*)d_in[9];
  const float* bih1   = (const float*)d_in[10];
  const float* bhh1   = (const float*)d_in[11];
  const float* fcw    = (const float*)d_in[12];
  const float* fcb    = (const float*)d_in[13];

  char* ws = (char*)d_ws;
  size_t off = 0;
  auto alloc = [&](size_t bytes) {
    void* p = ws + off;
    off += (bytes + 255) & ~(size_t)255;
    return p;
  };
  unsigned short* wih0b = (unsigned short*)alloc((size_t)2 * G4 * E_ * 2);
  unsigned short* whh0b = (unsigned short*)alloc((size_t)2 * G4 * H_ * 2);
  unsigned short* wih1b = (unsigned short*)alloc((size_t)2 * G4 * 1024 * 2);
  unsigned short* whh1b = (unsigned short*)alloc((size_t)2 * G4 * H_ * 2);
  unsigned short* fcwb  = (unsigned short*)alloc((size_t)V_ * 1024 * 2);
  unsigned short* Xb    = (unsigned short*)alloc((size_t)SB * E_ * 2);
  unsigned short* H0    = (unsigned short*)alloc((size_t)SB * 1024 * 2);
  unsigned short* O1    = (unsigned short*)alloc((size_t)SB * 1024 * 2);
  unsigned short* h0i   = (unsigned short*)alloc((size_t)2 * B_ * H_ * 2);
  unsigned short* h1i   = (unsigned short*)alloc((size_t)2 * B_ * H_ * 2);
  float* b0s = (float*)alloc((size_t)2 * G4 * 4);
  float* b1s = (float*)alloc((size_t)2 * G4 * 4);
  unsigned* cnt0 = (unsigned*)alloc(CNT_BYTES);
  unsigned* cnt1 = (unsigned*)alloc(CNT_BYTES);
  (void)ws_size;

  // --- prep ---
  k_f2bf4<<<2048, 256, 0, stream>>>(wih0, whh0, wih1, whh1, wih0b);
  k_f2bf<<<4096, 256, 0, stream>>>(fcw, fcwb, V_ * 1024);
  k_addbias<<<16, 256, 0, stream>>>(bih0, bhh0, b0s, 2 * G4);
  k_addbias<<<16, 256, 0, stream>>>(bih1, bhh1, b1s, 2 * G4);
  k_gather<<<SB, 256, 0, stream>>>(Y, emb, Xb);
  k_init_h<<<512, 256, 0, stream>>>(hidden, h0i, h1i);
  (void)hipMemsetAsync(cnt0, 0, CNT_BYTES, stream);
  (void)hipMemsetAsync(cnt1, 0, CNT_BYTES, stream);

  // --- layer-0 input gates -> bf16 G0 in d_out row tails ---
  k_gemm_g0<<<1024, 256, 0, stream>>>(Xb, wih0b, b0s, (unsigned short*)d_out,
                                      E_, SB / 128, 1024);

  // --- fused persistent recurrence (self-timed chains, R15 structure) ---
  k_fused_lstm<<<NBLK, 256, 0, stream>>>(h0i, h1i, cell, whh0b, wih1b, whh1b,
                                         b1s, (const unsigned short*)d_out,
                                         H0, O1, cnt0, cnt1);

  // --- final projection: 256^2 counted-vmcnt pipelined GEMM (bn-major/XCD) ---
  k_gemm_fc256<<<2000, 512, 0, stream>>>(O1, fcwb, fcb, (float*)d_out);
}

// Round 20
// 1070.176 us; speedup vs baseline: 2.9322x; 1.0121x over previous
//
#include <hip/hip_runtime.h>
#include <hip/hip_bf16.h>
#include <stdint.h>

#define S_ 64
#define B_ 64
#define E_ 512
#define H_ 512
#define V_ 32000
#define G4 2048   // 4*H
#define SB 4096   // S*B

// d_out row = 32000 fp32 = 64000 ushort; G0 (bf16) lives in the tail 4096
// ushorts of each row. Sequential: final GEMM overwrites tails after rec.
#define OROW_US 64000
#define GTAIL_US 59904   // 29952 fp32 * 2

typedef __attribute__((ext_vector_type(8))) short short8;
typedef __attribute__((ext_vector_type(4))) float f32x4;
typedef __attribute__((ext_vector_type(4))) int i32x4;

static __device__ __forceinline__ unsigned short f2bf(float f) {
  unsigned u = __float_as_uint(f);
  u += 0x7fff + ((u >> 16) & 1);   // RNE
  return (unsigned short)(u >> 16);
}
static __device__ __forceinline__ unsigned pk2(float a, float b) {
  return (unsigned)f2bf(a) | ((unsigned)f2bf(b) << 16);
}
static __device__ __forceinline__ float bf2f(unsigned short u) {
  return __uint_as_float((unsigned)u << 16);
}
// fast gate activations via native v_exp_f32 (exp2)
static __device__ __forceinline__ float sigm(float x) {
  return 1.f / (1.f + exp2f(x * -1.44269504f));
}
static __device__ __forceinline__ float tanh_fast(float x) {
  float e = exp2f(x * 2.88539008f);   // e^(2x)
  return 1.f - 2.f / (e + 1.f);
}

__device__ __forceinline__ void gload_lds16(const void* g, void* l) {
  __builtin_amdgcn_global_load_lds(
      (const __attribute__((address_space(1))) void*)g,
      (__attribute__((address_space(3))) void*)l, 16, 0, 0);
}

// coherent (device-visible) 16-byte store: write-through past the XCD L2
__device__ __forceinline__ void st128_sys(void* p, i32x4 v) {
  asm volatile("global_store_dwordx4 %0, %1, off sc0 sc1"
               :: "v"((unsigned long long)p), "v"(v) : "memory");
}
__device__ __forceinline__ void wait_vm0() {
  asm volatile("s_waitcnt vmcnt(0)" ::: "memory");
}

__device__ __forceinline__ void spin_ge(unsigned* c, unsigned tgt) {
  while (__hip_atomic_load(c, __ATOMIC_RELAXED, __HIP_MEMORY_SCOPE_AGENT) < tgt)
    __builtin_amdgcn_s_sleep(1);
}
__device__ __forceinline__ void arrive(unsigned* c) {
  __hip_atomic_fetch_add(c, 1u, __ATOMIC_RELAXED, __HIP_MEMORY_SCOPE_AGENT);
}

#define CIDX(t, d, p) ((((t) * 8) + ((d) * 4) + (p)) * 64)
#define CNT_BYTES (64 * 8 * 64 * 4)

__global__ void k_f2bf4(const float* __restrict__ s0, const float* __restrict__ s1,
                        const float* __restrict__ s2, const float* __restrict__ s3,
                        unsigned short* __restrict__ dst) {
  const int c0 = 2 * G4 * E_ / 8, c1 = c0 + 2 * G4 * H_ / 8,
            c2 = c1 + 2 * G4 * 1024 / 8, c3 = c2 + 2 * G4 * H_ / 8;
  int i8 = blockIdx.x * blockDim.x + threadIdx.x;
  int stride = gridDim.x * blockDim.x;
  for (; i8 < c3; i8 += stride) {
    const float* s; int o8;
    if (i8 < c0) { s = s0; o8 = i8; }
    else if (i8 < c1) { s = s1; o8 = i8 - c0; }
    else if (i8 < c2) { s = s2; o8 = i8 - c1; }
    else { s = s3; o8 = i8 - c2; }
    int o = o8 * 8;
    float4 x = *(const float4*)&s[o];
    float4 y = *(const float4*)&s[o + 4];
    i32x4 v = {(int)pk2(x.x, x.y), (int)pk2(x.z, x.w),
               (int)pk2(y.x, y.y), (int)pk2(y.z, y.w)};
    *(i32x4*)&dst[i8 * 8] = v;
  }
}

__global__ void k_f2bf(const float* __restrict__ in, unsigned short* __restrict__ out, int n) {
  int i = blockIdx.x * blockDim.x + threadIdx.x;
  int stride = gridDim.x * blockDim.x;
  for (; i < n; i += stride) out[i] = f2bf(in[i]);
}

// merged small-prep kernel: [0,4096) embedding gather; [4096,4608) init_h;
// [4608,4640) bias sums (b0s|b1s).
__global__ void k_prep(const int* __restrict__ Y, const float* __restrict__ emb,
                       unsigned short* __restrict__ X,
                       const float* __restrict__ hid,
                       unsigned short* __restrict__ h0i, unsigned short* __restrict__ h1i,
                       const float* __restrict__ bih0, const float* __restrict__ bhh0,
                       const float* __restrict__ bih1, const float* __restrict__ bhh1,
                       float* __restrict__ bsum) {
  int blk = blockIdx.x;
  if (blk < 4096) {
    int sb = blk;
    int t = sb >> 6, b = sb & 63;
    int idx = (t == 0) ? Y[b * S_ + 1] : Y[b * S_ + t - 1];
    const float* src = emb + (size_t)idx * E_;
    unsigned short* dst = X + (size_t)sb * E_;
    for (int e = threadIdx.x; e < E_; e += blockDim.x) dst[e] = f2bf(src[e]);
  } else if (blk < 4608) {
    int i = (blk - 4096) * 256 + threadIdx.x;
    if (i < 4 * B_ * H_) {
      unsigned short v = f2bf(hid[i]);
      if (i < 2 * B_ * H_) h0i[i] = v;
      else h1i[i - 2 * B_ * H_] = v;
    }
  } else {
    int i = (blk - 4608) * 256 + threadIdx.x;
    if (i < 2 * G4) bsum[i] = bih0[i] + bhh0[i];
    else if (i < 4 * G4) bsum[i] = bih1[i - 2 * G4] + bhh1[i - 2 * G4];
  }
}

// ---------------- G0 GEMM: bf16 into d_out row tails (R10-proven) ----------------
__global__ __launch_bounds__(256) void k_gemm_g0(
    const unsigned short* __restrict__ A, const unsigned short* __restrict__ B,
    const float* __restrict__ bias, unsigned short* __restrict__ C,
    int K, int nTM, int nwg) {
  __shared__ unsigned short Als[128 * 32];
  __shared__ unsigned short Bls[128 * 32];
  int tid = threadIdx.x;
  int o = blockIdx.x;
  int wg = (o & 7) * (nwg >> 3) + (o >> 3);
  int bm = wg % nTM, bn = wg / nTM;
  int w = tid >> 6, l = tid & 63;
  int wr = w >> 1, wc = w & 1;
  int lr = l & 15, hi = l >> 4;
  int c0 = w * 128 + l;
  int row0 = c0 >> 2, ks0 = (((c0 & 3) ^ (row0 & 3)) * 8);
  int c1 = c0 + 64;
  int row1 = c1 >> 2, ks1 = (((c1 & 3) ^ (row1 & 3)) * 8);
  const unsigned short* Ab = A + (size_t)(bm * 128) * K;
  const unsigned short* Bb = B + (size_t)(bn * 128) * K;
  unsigned short* AlsW = &Als[w * 1024];
  unsigned short* BlsW = &Bls[w * 1024];
  int co = ((hi ^ (lr & 3)) * 8);
  f32x4 acc[4][4] = {};
  for (int kk = 0; kk < K; kk += 32) {
    __syncthreads();
    gload_lds16(Ab + (size_t)row0 * K + kk + ks0, AlsW);
    gload_lds16(Ab + (size_t)row1 * K + kk + ks1, AlsW + 512);
    gload_lds16(Bb + (size_t)row0 * K + kk + ks0, BlsW);
    gload_lds16(Bb + (size_t)row1 * K + kk + ks1, BlsW + 512);
    __syncthreads();
    short8 af[4], bfr[4];
#pragma unroll
    for (int r = 0; r < 4; r++)
      af[r] = *(const short8*)&Als[(wr * 64 + r * 16 + lr) * 32 + co];
#pragma unroll
    for (int c4 = 0; c4 < 4; c4++)
      bfr[c4] = *(const short8*)&Bls[(wc * 64 + c4 * 16 + lr) * 32 + co];
#pragma unroll
    for (int r = 0; r < 4; r++)
#pragma unroll
      for (int c4 = 0; c4 < 4; c4++)
        acc[r][c4] = __builtin_amdgcn_mfma_f32_16x16x32_bf16(af[r], bfr[c4], acc[r][c4], 0, 0, 0);
  }
  int rbase = bm * 128 + wr * 64 + hi * 4;
  int cbase = bn * 128 + wc * 64 + lr;
#pragma unroll
  for (int r = 0; r < 4; r++) {
#pragma unroll
    for (int c4 = 0; c4 < 4; c4++) {
      int cc = cbase + c4 * 16;
      float bv = bias[cc];
#pragma unroll
      for (int j = 0; j < 4; j++) {
        int rr = rbase + r * 16 + j;
        C[(size_t)rr * OROW_US + GTAIL_US + cc] = f2bf(acc[r][c4][j] + bv);
      }
    }
  }
}

// ------- final GEMM: 256x256 tile, BK=64, counted-vmcnt pipeline (R19-proven) -------
__global__ __launch_bounds__(512, 1) void k_gemm_fc256(
    const unsigned short* __restrict__ A,   // O1 (4096,1024) bf16
    const unsigned short* __restrict__ B,   // fcwb (32000,1024) bf16
    const float* __restrict__ bias, float* __restrict__ C) {
  __shared__ unsigned short LB[65536];      // 131072 B
  int tid = threadIdx.x;
  int w = tid >> 6, l = tid & 63;
  int lr = l & 15, hi = l >> 4;
  int wm = w >> 2, wn = w & 3;
  int o = blockIdx.x;
  int wg = (o & 7) * 250 + (o >> 3);        // bijective XCD swizzle (2000%8==0)
  int bn = wg % 125, bm = wg / 125;         // bn-major within XCD (A L2-resident)
  const unsigned short* Ab = A + (size_t)(bm * 256) * 1024;
  const unsigned short* Bb = B + (size_t)(bn * 256) * 1024;
  int srcoff[4], cb[4];
#pragma unroll
  for (int r = 0; r < 4; r++) {
    int c = r * 512 + tid;
    int row = c >> 3, stc = c & 7;
    srcoff[r] = row * 1024 + (stc ^ (row & 7)) * 8;
    cb[r] = (r * 512 + w * 64) * 8;         // wave-uniform LDS elem base
  }
  auto stage = [&](int kt) {
    int slot = (kt & 1) * 32768;
#pragma unroll
    for (int r = 0; r < 4; r++)
      gload_lds16(Ab + srcoff[r] + kt * 64, &LB[slot + cb[r]]);
#pragma unroll
    for (int r = 0; r < 4; r++)
      gload_lds16(Bb + srcoff[r] + kt * 64, &LB[slot + 16384 + cb[r]]);
  };
  f32x4 acc[8][4] = {};
  stage(0);
  stage(1);
  for (int t = 0; t < 16; ++t) {
    if (t < 15) asm volatile("s_waitcnt vmcnt(8)" ::: "memory");
    else        asm volatile("s_waitcnt vmcnt(0)" ::: "memory");
    __builtin_amdgcn_s_barrier();
    __builtin_amdgcn_sched_barrier(0);
    const unsigned short* bufA = &LB[(t & 1) * 32768];
    const unsigned short* bufB = bufA + 16384;
    __builtin_amdgcn_s_setprio(1);
#pragma unroll
    for (int kh = 0; kh < 2; kh++) {
      short8 af[8], bf[4];
      int ch = ((kh * 4 + hi) ^ (lr & 7)) * 8;
#pragma unroll
      for (int mf = 0; mf < 8; mf++)
        af[mf] = *(const short8*)&bufA[(wm * 128 + mf * 16 + lr) * 64 + ch];
#pragma unroll
      for (int nf = 0; nf < 4; nf++)
        bf[nf] = *(const short8*)&bufB[(wn * 64 + nf * 16 + lr) * 64 + ch];
#pragma unroll
      for (int mf = 0; mf < 8; mf++)
#pragma unroll
        for (int nf = 0; nf < 4; nf++)
          acc[mf][nf] = __builtin_amdgcn_mfma_f32_16x16x32_bf16(af[mf], bf[nf], acc[mf][nf], 0, 0, 0);
    }
    __builtin_amdgcn_s_setprio(0);
    __builtin_amdgcn_sched_barrier(0);
    __builtin_amdgcn_s_barrier();
    if (t + 2 < 16) stage(t + 2);
  }
#pragma unroll
  for (int mf = 0; mf < 8; mf++) {
#pragma unroll
    for (int nf = 0; nf < 4; nf++) {
      int cc = bn * 256 + wn * 64 + nf * 16 + lr;
      float bv = bias[cc];
#pragma unroll
      for (int j = 0; j < 4; j++) {
        int rr = bm * 256 + wm * 128 + mf * 16 + hi * 4 + j;
        size_t orow = (size_t)((rr & 63) * 64 + (rr >> 6));   // (S,B)->(B,S)
        __builtin_nontemporal_store(acc[mf][nf][j] + bv, &C[orow * (size_t)V_ + cc]);
      }
    }
  }
}

// ---------------- fused persistent 2-layer bidirectional LSTM (R15/R17-proven) ----------------
#define LDW0 520    // l0: 64 rows x (512+8)
#define LDW1 1544   // l1: 32 rows x (1536+8)
#define NBLK 192

__global__ __launch_bounds__(256) void k_fused_lstm(
    const unsigned short* __restrict__ h0i,   // (2,B,H) bf16
    const unsigned short* __restrict__ h1i,   // (2,B,H) bf16
    const float* __restrict__ cell,           // (4,B,H) fp32 [l0f,l0b,l1f,l1b]
    const unsigned short* __restrict__ whh0,  // (2,2048,512) bf16
    const unsigned short* __restrict__ wih1,  // (2,2048,1024) bf16
    const unsigned short* __restrict__ whh1,  // (2,2048,512) bf16
    const float* __restrict__ b1s,            // (2,2048) fp32
    const unsigned short* __restrict__ G0u,   // d_out as ushort (bf16 G0 tails)
    unsigned short* __restrict__ H0,          // (SB,1024) bf16
    unsigned short* __restrict__ O1,          // (SB,1024) bf16
    unsigned* __restrict__ cnt0, unsigned* __restrict__ cnt1) {
  __shared__ unsigned short SM[32 * LDW1];    // 98,816 B
  __shared__ __align__(16) unsigned short HS[64 * 16];
  int tid = threadIdx.x;
  int w = tid >> 6, l = tid & 63;
  int lr = l & 15, hi = l >> 4;

  if (blockIdx.x < 64) {
    // ================= LAYER 0 =================
    int d = blockIdx.x >> 5, jt = blockIdx.x & 31;
    const unsigned short* Wd = whh0 + (size_t)d * (G4 * H_);
    for (int c = tid; c < 64 * 64; c += 256) {
      int row = c >> 6, ck = c & 63;
      int g = row >> 4, r16 = row & 15;
      *(int4*)&SM[row * LDW0 + ck * 8] =
          *(const int4*)&Wd[(size_t)(g * H_ + jt * 16 + r16) * H_ + ck * 8];
    }
    int j = jt * 16 + lr;
    int b0 = w * 16 + hi * 4;
    f32x4 creg;
    {
      const float* cd = cell + (size_t)d * (B_ * H_);
#pragma unroll
      for (int jj = 0; jj < 4; jj++) creg[jj] = cd[(size_t)(b0 + jj) * H_ + j];
    }
    __syncthreads();
    float gv[4][4];
    auto preloadG = [&](int t) {
#pragma unroll
      for (int jj = 0; jj < 4; jj++) {
        const unsigned short* Gb =
            G0u + (size_t)(t * B_ + b0 + jj) * OROW_US + GTAIL_US + d * 2048 + j;
#pragma unroll
        for (int g = 0; g < 4; g++) gv[g][jj] = bf2f(Gb[g * 512]);
      }
    };
    preloadG(0);
    for (int t = 0; t < S_; ++t) {
      if (t >= 1) {
        if (tid < 4) spin_ge(&cnt0[CIDX(t - 1, d, tid)], 8);
        __syncthreads();
      }
      const unsigned short* hp = (t == 0) ? h0i + (size_t)d * (B_ * H_)
                                          : H0 + (size_t)(t - 1) * B_ * 1024 + d * 512;
      size_t hstr = (t == 0) ? (size_t)H_ : 1024;
      const unsigned short* arow = hp + (size_t)(w * 16 + lr) * hstr + hi * 8;
      f32x4 acc[4] = {};
#pragma unroll
      for (int ki = 0; ki < 16; ki++) {
        short8 a = *(const short8*)&arow[ki * 32];
#pragma unroll
        for (int g = 0; g < 4; g++) {
          short8 bfr = *(const short8*)&SM[(g * 16 + lr) * LDW0 + ki * 32 + hi * 8];
          acc[g] = __builtin_amdgcn_mfma_f32_16x16x32_bf16(a, bfr, acc[g], 0, 0, 0);
        }
      }
#pragma unroll
      for (int jj = 0; jj < 4; jj++) {
        float gi = acc[0][jj] + gv[0][jj];
        float gf = acc[1][jj] + gv[1][jj];
        float gg = acc[2][jj] + gv[2][jj];
        float go = acc[3][jj] + gv[3][jj];
        float c = sigm(gf) * creg[jj] + sigm(gi) * tanh_fast(gg);
        creg[jj] = c;
        HS[(b0 + jj) * 16 + lr] = f2bf(sigm(go) * tanh_fast(c));
      }
      __syncthreads();
      unsigned short* Ho = H0 + (size_t)t * B_ * 1024 + d * 512 + jt * 16;
      if (tid < 128) {
        int r = tid >> 1, half = tid & 1;
        st128_sys(&Ho[(size_t)r * 1024 + half * 8], *(const i32x4*)&HS[r * 16 + half * 8]);
      }
      wait_vm0();
      __syncthreads();
      if (tid == 0) arrive(&cnt0[CIDX(t, d, jt & 3)]);
      if (t + 1 < S_) preloadG(t + 1);
    }
  } else {
    // ================= LAYER 1 (pipelined) =================
    int idx = blockIdx.x - 64;
    int d = idx >> 6, jt8 = idx & 63;
    int j0 = jt8 * 8;
    {
      const unsigned short* Wih = wih1 + (size_t)d * (G4 * 1024);
      const unsigned short* Whh = whh1 + (size_t)d * (G4 * H_);
      for (int c = tid; c < 32 * 192; c += 256) {
        int r = c / 192, ck = c - r * 192;
        int g = r >> 3, jc = r & 7;
        const unsigned short* src =
            (ck < 128) ? Wih + (size_t)(g * H_ + j0 + jc) * 1024 + ck * 8
                       : Whh + (size_t)(g * H_ + j0 + jc) * H_ + (ck - 128) * 8;
        *(int4*)&SM[r * LDW1 + ck * 8] = *(const int4*)src;
      }
    }
    int j = j0 + (lr & 7);
    const float* b1d = b1s + d * G4;
    float bi_ = b1d[j], bf_ = b1d[512 + j], bg_ = b1d[1024 + j], bo_ = b1d[1536 + j];
    int b0 = w * 16 + hi * 4;
    f32x4 creg = {};
    if (lr < 8) {
      const float* cd = cell + (size_t)(2 + d) * (B_ * H_);
#pragma unroll
      for (int jj = 0; jj < 4; jj++) creg[jj] = cd[(size_t)(b0 + jj) * H_ + j];
    }
    __syncthreads();

    f32x4 acc0, acc1;
    {
      if (tid < 8) spin_ge(&cnt0[CIDX(0, 0, 0) + tid * 64], 8);
      __syncthreads();
      acc0 = (f32x4){}; acc1 = (f32x4){};
      const unsigned short* x1row = H0 + ((size_t)0 * B_ + w * 16 + lr) * 1024 + hi * 8;
#pragma unroll
      for (int ki = 0; ki < 32; ki++) {
        short8 a = *(const short8*)&x1row[ki * 32];
        short8 bA = *(const short8*)&SM[(size_t)lr * LDW1 + ki * 32 + hi * 8];
        short8 bB = *(const short8*)&SM[(size_t)(16 + lr) * LDW1 + ki * 32 + hi * 8];
        acc0 = __builtin_amdgcn_mfma_f32_16x16x32_bf16(a, bA, acc0, 0, 0, 0);
        acc1 = __builtin_amdgcn_mfma_f32_16x16x32_bf16(a, bB, acc1, 0, 0, 0);
      }
    }
    for (int t = 0; t < S_; ++t) {
      if (t >= 1) {
        if (tid < 4) spin_ge(&cnt1[CIDX(t - 1, d, tid)], 16);
        __syncthreads();
      }
      const unsigned short* hprev = (t == 0)
          ? h1i + (size_t)d * (B_ * H_) + (size_t)(w * 16 + lr) * H_ + hi * 8
          : O1 + ((size_t)(t - 1) * B_ + w * 16 + lr) * 1024 + d * 512 + hi * 8;
#pragma unroll
      for (int ki = 0; ki < 16; ki++) {
        short8 a = *(const short8*)&hprev[ki * 32];
        short8 bA = *(const short8*)&SM[(size_t)lr * LDW1 + 1024 + ki * 32 + hi * 8];
        short8 bB = *(const short8*)&SM[(size_t)(16 + lr) * LDW1 + 1024 + ki * 32 + hi * 8];
        acc0 = __builtin_amdgcn_mfma_f32_16x16x32_bf16(a, bA, acc0, 0, 0, 0);
        acc1 = __builtin_amdgcn_mfma_f32_16x16x32_bf16(a, bB, acc1, 0, 0, 0);
      }
      float pf[4], po[4];
#pragma unroll
      for (int jj = 0; jj < 4; jj++) {
        pf[jj] = __shfl_xor(acc0[jj], 8);
        po[jj] = __shfl_xor(acc1[jj], 8);
      }
      if (lr < 8) {
#pragma unroll
        for (int jj = 0; jj < 4; jj++) {
          float gi = acc0[jj] + bi_;
          float gf = pf[jj] + bf_;
          float gg = acc1[jj] + bg_;
          float go = po[jj] + bo_;
          float c = sigm(gf) * creg[jj] + sigm(gi) * tanh_fast(gg);
          creg[jj] = c;
          HS[(b0 + jj) * 8 + lr] = f2bf(sigm(go) * tanh_fast(c));
        }
      }
      __syncthreads();
      unsigned short* Oo = O1 + (size_t)t * B_ * 1024 + d * 512 + j0;
      if (tid < 64) st128_sys(&Oo[(size_t)tid * 1024], *(const i32x4*)&HS[tid * 8]);
      wait_vm0();
      __syncthreads();
      if (tid == 0 && t + 1 < S_) arrive(&cnt1[CIDX(t, d, jt8 & 3)]);
      if (t + 1 < S_) {
        if (tid < 8) spin_ge(&cnt0[CIDX(t + 1, 0, 0) + tid * 64], 8);
        __syncthreads();
        acc0 = (f32x4){}; acc1 = (f32x4){};
        const unsigned short* x1row =
            H0 + ((size_t)(t + 1) * B_ + w * 16 + lr) * 1024 + hi * 8;
#pragma unroll
        for (int ki = 0; ki < 32; ki++) {
          short8 a = *(const short8*)&x1row[ki * 32];
          short8 bA = *(const short8*)&SM[(size_t)lr * LDW1 + ki * 32 + hi * 8];
          short8 bB = *(const short8*)&SM[(size_t)(16 + lr) * LDW1 + ki * 32 + hi * 8];
          acc0 = __builtin_amdgcn_mfma_f32_16x16x32_bf16(a, bA, acc0, 0, 0, 0);
          acc1 = __builtin_amdgcn_mfma_f32_16x16x32_bf16(a, bB, acc1, 0, 0, 0);
        }
      }
    }
  }
}

extern "C" void kernel_launch(void* const* d_in, const int* in_sizes, int n_in,
                              void* d_out, int out_size, void* d_ws, size_t ws_size,
                              hipStream_t stream) {
  const float* hidden = (const float*)d_in[0];
  const float* cell   = (const float*)d_in[1];
  const int*   Y      = (const int*)d_in[2];
  const float* emb    = (const float*)d_in[3];
  const float* wih0   = (const float*)d_in[4];
  const float* whh0   = (const float*)d_in[5];
  const float* bih0   = (const float*)d_in[6];
  const float* bhh0   = (const float*)d_in[7];
  const float* wih1   = (const float*)d_in[8];
  const float* whh1   = (const float*)d_in[9];
  const float* bih1   = (const float*)d_in[10];
  const float* bhh1   = (const float*)d_in[11];
  const float* fcw    = (const float*)d_in[12];
  const float* fcb    = (const float*)d_in[13];

  char* ws = (char*)d_ws;
  size_t off = 0;
  auto alloc = [&](size_t bytes) {
    void* p = ws + off;
    off += (bytes + 255) & ~(size_t)255;
    return p;
  };
  unsigned short* wih0b = (unsigned short*)alloc((size_t)2 * G4 * E_ * 2);
  unsigned short* whh0b = (unsigned short*)alloc((size_t)2 * G4 * H_ * 2);
  unsigned short* wih1b = (unsigned short*)alloc((size_t)2 * G4 * 1024 * 2);
  unsigned short* whh1b = (unsigned short*)alloc((size_t)2 * G4 * H_ * 2);
  unsigned short* fcwb  = (unsigned short*)alloc((size_t)V_ * 1024 * 2);
  unsigned short* Xb    = (unsigned short*)alloc((size_t)SB * E_ * 2);
  unsigned short* H0    = (unsigned short*)alloc((size_t)SB * 1024 * 2);
  unsigned short* O1    = (unsigned short*)alloc((size_t)SB * 1024 * 2);
  unsigned short* h0i   = (unsigned short*)alloc((size_t)2 * B_ * H_ * 2);
  unsigned short* h1i   = (unsigned short*)alloc((size_t)2 * B_ * H_ * 2);
  float* bsum = (float*)alloc((size_t)4 * G4 * 4);   // [b0s | b1s]
  unsigned* cnt0 = (unsigned*)alloc(CNT_BYTES);
  unsigned* cnt1 = (unsigned*)alloc(CNT_BYTES);
  (void)ws_size;

  // --- prep ---
  k_f2bf4<<<2048, 256, 0, stream>>>(wih0, whh0, wih1, whh1, wih0b);
  k_f2bf<<<4096, 256, 0, stream>>>(fcw, fcwb, V_ * 1024);
  k_prep<<<4640, 256, 0, stream>>>(Y, emb, Xb, hidden, h0i, h1i,
                                   bih0, bhh0, bih1, bhh1, bsum);
  (void)hipMemsetAsync(cnt0, 0, CNT_BYTES, stream);
  (void)hipMemsetAsync(cnt1, 0, CNT_BYTES, stream);

  // --- layer-0 input gates -> bf16 G0 in d_out row tails ---
  k_gemm_g0<<<1024, 256, 0, stream>>>(Xb, wih0b, bsum, (unsigned short*)d_out,
                                      E_, SB / 128, 1024);

  // --- fused persistent recurrence (self-timed chains, R15 structure) ---
  k_fused_lstm<<<NBLK, 256, 0, stream>>>(h0i, h1i, cell, whh0b, wih1b, whh1b,
                                         bsum + 2 * G4, (const unsigned short*)d_out,
                                         H0, O1, cnt0, cnt1);

  // --- final projection: 256^2 counted-vmcnt pipelined GEMM (bn-major/XCD) ---
  k_gemm_fc256<<<2000, 512, 0, stream>>>(O1, fcwb, fcb, (float*)d_out);
}